// Round 1
// 96.163 us; speedup vs baseline: 1.0580x; 1.0580x over previous
//
#include <hip/hip_runtime.h>

#define NUM_V 100000
#define NUM_R 1000
#define ARITY 3
#define DD 128
#define DI 192   /* D + I */
#define HH 128
#define BB 4096
#define NN 64

typedef __attribute__((ext_vector_type(8))) short short8;
typedef __attribute__((ext_vector_type(4))) float f32x4;
typedef __attribute__((ext_vector_type(4))) unsigned int u32x4;
typedef __attribute__((ext_vector_type(8))) _Float16 half8;
typedef __attribute__((ext_vector_type(2))) _Float16 half2v;

__device__ inline unsigned short f2bf(float f) {
    unsigned int u = __float_as_uint(f);
    unsigned int r = (u + 0x7fffu + ((u >> 16) & 1u)) >> 16;
    return (unsigned short)r;
}
__device__ inline float bf2f(unsigned short s) {
    return __uint_as_float(((unsigned int)s) << 16);
}

// split pair (f0,f1) -> {hi: packed truncated bf16 pair, lo: packed RNE bf16 of residual}
__device__ inline uint2 splitpair(float f0, float f1) {
    unsigned int u0 = __float_as_uint(f0), u1 = __float_as_uint(f1);
    unsigned int hp = __builtin_amdgcn_perm(u1, u0, 0x07060302u);  // {u0.hi16, u1.hi16}
    float r0 = f0 - __uint_as_float(u0 & 0xffff0000u);
    float r1 = f1 - __uint_as_float(u1 & 0xffff0000u);
    unsigned int lp = (unsigned int)f2bf(r0) | ((unsigned int)f2bf(r1) << 16);
    return make_uint2(hp, lp);
}

// async global->LDS, 16B per lane; LDS dest is wave-uniform base + lane*16
__device__ inline void gload16(const void* g, void* lds) {
    __builtin_amdgcn_global_load_lds(
        (const __attribute__((address_space(1))) unsigned int*)g,
        (__attribute__((address_space(3))) unsigned int*)lds, 16, 0, 0);
}

// ---------------- Kernel A: peProd[h] = prod_a (P[a]@WP + bP)[h] -------------
__global__ __launch_bounds__(128) void pe_kernel(const float* __restrict__ P,
                                                 const float* __restrict__ WP,
                                                 const float* __restrict__ bP,
                                                 float* __restrict__ peProd) {
    int h = threadIdx.x;
    float prod = 1.0f;
    for (int a = 0; a < ARITY; ++a) {
        float acc = bP[h];
        for (int d = 0; d < DD; ++d) acc += P[a * DD + d] * WP[d * HH + h];
        prod *= acc;
    }
    peProd[h] = prod;
}

// ---------------- W-fragment precompute (split-bf16, MFMA layout) ------------
// wf layout: [kstep(6)][ctile(8)][split(2)][lane(64)][j(8)] ushort
__global__ __launch_bounds__(64) void wfrag_kernel(const float* __restrict__ W, // [DI][HH]
                                                   unsigned short* __restrict__ wf) {
    const int ks = blockIdx.x >> 3;  // 0..5
    const int ct = blockIdx.x & 7;   // 0..7
    const int l = threadIdx.x;       // 0..63
    const int col = ct * 16 + (l & 15);
    const int k0 = ks * 32 + (l >> 4) * 8;
    unsigned short hi[8], lo[8];
#pragma unroll
    for (int j = 0; j < 8; ++j) {
        float v = W[(size_t)(k0 + j) * HH + col];
        unsigned short h = f2bf(v);
        hi[j] = h;
        lo[j] = f2bf(v - bf2f(h));
    }
    size_t base = (size_t)(ks * 8 + ct) * 2 * 512;
#pragma unroll
    for (int j = 0; j < 8; ++j) wf[base + l * 8 + j] = hi[j];
#pragma unroll
    for (int j = 0; j < 8; ++j) wf[base + 512 + l * 8 + j] = lo[j];
}

// ---------------- LDS-staged MFMA GEMM (m97-style) ---------------------------
// C(fp16) = A @ W + bias. 64-row tile, 4 waves (2 row-halves x 2 col-halves).
// A staged via global_load_lds (coalesced 128B segments) with XOR chunk-swizzle
// (pre-swizzled SOURCE + swizzled ds_read, rule #21). Double-buffered LDS,
// one barrier per K-step (T3 minimal recipe). B loaded reg-direct from L2,
// issued BEFORE the A-stage so the compiler's counted vmcnt on B leaves the
// stage in flight.
__global__ __launch_bounds__(256, 4) void gemm_lds(const float* __restrict__ A,
                                                   const unsigned short* __restrict__ wf,
                                                   const float* __restrict__ bias,
                                                   _Float16* __restrict__ C, int M) {
    __shared__ float at[2][64 * 32];  // 8 KB per buffer, chunk-swizzled rows of 128B

    const int tid = threadIdx.x;
    const int l = tid & 63;
    const int wv = tid >> 6;        // 0..3
    const int wr = wv >> 1;         // row half: rows wr*32 .. +32
    const int wc = wv & 1;          // col half: cols wc*64 .. +64
    const int blockRow = blockIdx.x * 64;

    // ---- staging addresses: thread t, issue i covers LDS bytes (i*256+t)*16
    // row = i*32 + (t>>3); chunkpos = t&7; source chunk = chunkpos ^ (row&7)
    const int srow = tid >> 3;                       // 0..31 (issue-0 local row)
    const int schunk = (tid & 7) ^ (srow & 7);       // same for issue 1 (row+32)
    const float* sptr0;
    const float* sptr1;
    {
        int r0 = blockRow + srow;      if (r0 >= M) r0 = M - 1;
        int r1 = blockRow + 32 + srow; if (r1 >= M) r1 = M - 1;
        sptr0 = A + (size_t)r0 * DI + schunk * 4;
        sptr1 = A + (size_t)r1 * DI + schunk * 4;
    }

    // ---- fragment ds_read offsets (floats), chunk-swizzled by row
    // lane needs A row R = wr*32 + rt*16 + (l&15), k-chunks 2q,2q+1 (q=l>>4)
    int aoff[2][2];
#pragma unroll
    for (int rt = 0; rt < 2; ++rt) {
        const int R = wr * 32 + rt * 16 + (l & 15);
        const int q = l >> 4;
#pragma unroll
        for (int k = 0; k < 2; ++k)
            aoff[rt][k] = R * 32 + (((2 * q + k) ^ (R & 7)) << 2);
    }

    f32x4 acc[2][4];
#pragma unroll
    for (int i = 0; i < 2; ++i)
#pragma unroll
        for (int j = 0; j < 4; ++j) acc[i][j] = (f32x4){0.f, 0.f, 0.f, 0.f};

#define STAGE(buf, ks)                                              \
    do {                                                            \
        gload16(sptr0 + (ks) * 32, &at[buf][wv * 256]);             \
        gload16(sptr1 + (ks) * 32, &at[buf][1024 + wv * 256]);      \
    } while (0)

    STAGE(0, 0);
    __syncthreads();  // drains stage-0 (compiler emits vmcnt(0) before s_barrier)

#pragma unroll
    for (int ks = 0; ks < 6; ++ks) {
        const int cur = ks & 1;

        // B fragments first (L2-resident, contiguous 1KB/instr) so the
        // counted vmcnt before MFMA leaves the A-stage outstanding.
        short8 bh[4], bl[4];
#pragma unroll
        for (int ct = 0; ct < 4; ++ct) {
            const unsigned short* bp = wf + (size_t)(ks * 8 + wc * 4 + ct) * 1024 + l * 8;
            bh[ct] = *(const short8*)bp;
            bl[ct] = *(const short8*)(bp + 512);
        }

        if (ks < 5) STAGE(cur ^ 1, ks + 1);  // prefetch next K-step into other buffer

        // LDS -> fragments (2-way bank aliasing only, free) + split-bf16 convert
        short8 ah[2], al[2];
#pragma unroll
        for (int rt = 0; rt < 2; ++rt) {
            f32x4 v0 = *(const f32x4*)&at[cur][aoff[rt][0]];
            f32x4 v1 = *(const f32x4*)&at[cur][aoff[rt][1]];
            uint2 s0 = splitpair(v0.x, v0.y);
            uint2 s1 = splitpair(v0.z, v0.w);
            uint2 s2 = splitpair(v1.x, v1.y);
            uint2 s3 = splitpair(v1.z, v1.w);
            u32x4 hp = {s0.x, s1.x, s2.x, s3.x};
            u32x4 lp = {s0.y, s1.y, s2.y, s3.y};
            ah[rt] = __builtin_bit_cast(short8, hp);
            al[rt] = __builtin_bit_cast(short8, lp);
        }

#pragma unroll
        for (int ct = 0; ct < 4; ++ct) {
#pragma unroll
            for (int rt = 0; rt < 2; ++rt) {
                acc[rt][ct] = __builtin_amdgcn_mfma_f32_16x16x32_bf16(ah[rt], bh[ct], acc[rt][ct], 0, 0, 0);
                acc[rt][ct] = __builtin_amdgcn_mfma_f32_16x16x32_bf16(ah[rt], bl[ct], acc[rt][ct], 0, 0, 0);
                acc[rt][ct] = __builtin_amdgcn_mfma_f32_16x16x32_bf16(al[rt], bh[ct], acc[rt][ct], 0, 0, 0);
            }
        }

        if (ks < 5) __syncthreads();  // publishes next buffer + retires this one
    }
#undef STAGE

    // epilogue: C[row][col] = fp16(acc + bias[col])  (col=l&15, row=(l>>4)*4+j)
#pragma unroll
    for (int ct = 0; ct < 4; ++ct) {
        int col = (wc * 4 + ct) * 16 + (l & 15);
        float b = bias[col];
#pragma unroll
        for (int rt = 0; rt < 2; ++rt) {
            int rbase = blockRow + wr * 32 + rt * 16 + (l >> 4) * 4;
#pragma unroll
            for (int j = 0; j < 4; ++j) {
                int row = rbase + j;
                if (row < M) C[(size_t)row * HH + col] = (_Float16)(acc[rt][ct][j] + b);
            }
        }
    }
}

// ---------------- fp32 row-projection -> fp16 table (small M: RW) ------------
template <int K>
__global__ __launch_bounds__(256) void proj_kernel(int M, const float* __restrict__ A,
                                                   const float* __restrict__ W,
                                                   const float* __restrict__ bias,
                                                   _Float16* __restrict__ out) {
    const int lane = threadIdx.x & 63;
    const int wave = threadIdx.x >> 6;
    const int wavesPerGrid = gridDim.x * 4;
    const int waveId = blockIdx.x * 4 + wave;
    const float2 b2 = ((const float2*)bias)[lane];
    const float2* __restrict__ W2 = (const float2*)W;

    for (int rowBase0 = waveId * 8; rowBase0 < M; rowBase0 += wavesPerGrid * 8) {
        const int rowBase = __builtin_amdgcn_readfirstlane(rowBase0);
        float2 acc[8];
#pragma unroll
        for (int r = 0; r < 8; ++r) acc[r] = make_float2(0.f, 0.f);
#pragma unroll 4
        for (int k4 = 0; k4 < K / 4; ++k4) {
            float4 v[8];
#pragma unroll
            for (int r = 0; r < 8; ++r)
                v[r] = ((const float4*)(A + (size_t)(rowBase + r) * K))[k4];
#pragma unroll
            for (int kk = 0; kk < 4; ++kk) {
                float2 w = W2[(k4 * 4 + kk) * 64 + lane];
#pragma unroll
                for (int r = 0; r < 8; ++r) {
                    float vv = (kk == 0) ? v[r].x : (kk == 1) ? v[r].y : (kk == 2) ? v[r].z : v[r].w;
                    acc[r].x += vv * w.x;
                    acc[r].y += vv * w.y;
                }
            }
        }
#pragma unroll
        for (int r = 0; r < 8; ++r) {
            if (rowBase + r < M) {
                half2v h;
                h.x = (_Float16)(acc[r].x + b2.x);
                h.y = (_Float16)(acc[r].y + b2.y);
                *(half2v*)(out + (size_t)(rowBase + r) * HH + lane * 2) = h;
            }
        }
    }
}

// ---------------- Gather - product - neighbor-sum (fp16 tables) --------------
// out[b,h] = peProd[h] * sum_n RWh[r[b,n]][h] * prod_a VWh[e[a,b,n]][h]
__global__ __launch_bounds__(256) void gather_kernel(const int* __restrict__ r,
                                                     const int* __restrict__ e,
                                                     const _Float16* __restrict__ VWh,
                                                     const _Float16* __restrict__ RWh,
                                                     const float* __restrict__ peProd,
                                                     float* __restrict__ out) {
    __shared__ int rIdx[NN];
    __shared__ int eIdx[ARITY][NN];
    __shared__ float4 partial[3][16][2];

    const int b = blockIdx.x;
    const int tid = threadIdx.x;

    if (tid < NN) {
        rIdx[tid] = r[b * NN + tid];
    } else {
        int t = tid - NN;
        eIdx[t >> 6][t & 63] = e[(size_t)(t >> 6) * BB * NN + b * NN + (t & 63)];
    }
    __syncthreads();

    const int lane = tid & 63;
    const int wv = tid >> 6;    // 0..3
    const int q = lane >> 4;    // neighbor sub-slot 0..3
    const int ho = lane & 15;   // h-octet: h = ho*8 .. +8

    float acc8[8];
#pragma unroll
    for (int k = 0; k < 8; ++k) acc8[k] = 0.f;

#pragma unroll
    for (int it = 0; it < 4; ++it) {
        int n = it * 16 + wv * 4 + q;
        half8 rw = *(const half8*)(RWh + (size_t)rIdx[n] * HH + ho * 8);
        half8 v0 = *(const half8*)(VWh + (size_t)eIdx[0][n] * HH + ho * 8);
        half8 v1 = *(const half8*)(VWh + (size_t)eIdx[1][n] * HH + ho * 8);
        half8 v2 = *(const half8*)(VWh + (size_t)eIdx[2][n] * HH + ho * 8);
        half8 p = rw * v0;
        p = p * v1;
        p = p * v2;
#pragma unroll
        for (int k = 0; k < 8; ++k) acc8[k] += (float)p[k];
    }

    // combine the 4 neighbor sub-slots (lane quarters share ho)
#pragma unroll
    for (int k = 0; k < 8; ++k) {
        acc8[k] += __shfl_xor(acc8[k], 16);
        acc8[k] += __shfl_xor(acc8[k], 32);
    }

    if (wv > 0 && lane < 16) {
        partial[wv - 1][ho][0] = make_float4(acc8[0], acc8[1], acc8[2], acc8[3]);
        partial[wv - 1][ho][1] = make_float4(acc8[4], acc8[5], acc8[6], acc8[7]);
    }
    __syncthreads();
    if (wv == 0 && lane < 16) {
        float4 s0 = make_float4(acc8[0], acc8[1], acc8[2], acc8[3]);
        float4 s1 = make_float4(acc8[4], acc8[5], acc8[6], acc8[7]);
#pragma unroll
        for (int g = 0; g < 3; ++g) {
            float4 t0 = partial[g][ho][0], t1 = partial[g][ho][1];
            s0.x += t0.x; s0.y += t0.y; s0.z += t0.z; s0.w += t0.w;
            s1.x += t1.x; s1.y += t1.y; s1.z += t1.z; s1.w += t1.w;
        }
        float4 p0 = ((const float4*)peProd)[ho * 2];
        float4 p1 = ((const float4*)peProd)[ho * 2 + 1];
        ((float4*)(out + (size_t)b * HH))[ho * 2] =
            make_float4(s0.x * p0.x, s0.y * p0.y, s0.z * p0.z, s0.w * p0.w);
        ((float4*)(out + (size_t)b * HH))[ho * 2 + 1] =
            make_float4(s1.x * p1.x, s1.y * p1.y, s1.z * p1.z, s1.w * p1.w);
    }
}

// ---------------- Launch -----------------------------------------------------
extern "C" void kernel_launch(void* const* d_in, const int* in_sizes, int n_in,
                              void* d_out, int out_size, void* d_ws, size_t ws_size,
                              hipStream_t stream) {
    const int* r = (const int*)d_in[0];
    const int* e = (const int*)d_in[1];
    const float* V = (const float*)d_in[2];
    const float* R = (const float*)d_in[3];
    const float* P = (const float*)d_in[4];
    const float* WV = (const float*)d_in[5];
    const float* bV = (const float*)d_in[6];
    const float* WR = (const float*)d_in[7];
    const float* bR = (const float*)d_in[8];
    const float* WP = (const float*)d_in[9];
    const float* bP = (const float*)d_in[10];
    float* out = (float*)d_out;

    // ws layout: VWh [NUM_V,H] fp16 | RWh [NUM_R,H] fp16 | peProd [H] f32 | Wfrag 96 KB
    _Float16* VWh = (_Float16*)d_ws;
    _Float16* RWh = VWh + (size_t)NUM_V * HH;
    float* peProd = (float*)(RWh + (size_t)NUM_R * HH);
    unsigned short* wfrag = (unsigned short*)(peProd + HH);

    pe_kernel<<<1, 128, 0, stream>>>(P, WP, bP, peProd);
    wfrag_kernel<<<48, 64, 0, stream>>>(WV, wfrag);
    proj_kernel<DD><<<32, 256, 0, stream>>>(NUM_R, R, WR, bR, RWh);
    gemm_lds<<<(NUM_V + 63) / 64, 256, 0, stream>>>(V, wfrag, bV, VWh, NUM_V);
    gather_kernel<<<BB, 256, 0, stream>>>(r, e, VWh, RWh, peProd, out);
}

// Round 2
// 85.720 us; speedup vs baseline: 1.1869x; 1.1218x over previous
//
#include <hip/hip_runtime.h>

#define NUM_V 100000
#define NUM_R 1000
#define ARITY 3
#define DD 128
#define DI 192   /* D + I */
#define HH 128
#define BB 4096
#define NN 64

typedef __attribute__((ext_vector_type(8))) short short8;
typedef __attribute__((ext_vector_type(4))) float f32x4;
typedef __attribute__((ext_vector_type(4))) unsigned int u32x4;
typedef __attribute__((ext_vector_type(8))) _Float16 half8;
typedef __attribute__((ext_vector_type(2))) _Float16 half2v;

__device__ inline unsigned short f2bf(float f) {
    unsigned int u = __float_as_uint(f);
    unsigned int r = (u + 0x7fffu + ((u >> 16) & 1u)) >> 16;
    return (unsigned short)r;
}
__device__ inline float bf2f(unsigned short s) {
    return __uint_as_float(((unsigned int)s) << 16);
}

// split pair (f0,f1) -> {hi: packed truncated bf16 pair, lo: packed RNE bf16 of residual}
__device__ inline uint2 splitpair(float f0, float f1) {
    unsigned int u0 = __float_as_uint(f0), u1 = __float_as_uint(f1);
    unsigned int hp = __builtin_amdgcn_perm(u1, u0, 0x07060302u);  // {u0.hi16, u1.hi16}
    float r0 = f0 - __uint_as_float(u0 & 0xffff0000u);
    float r1 = f1 - __uint_as_float(u1 & 0xffff0000u);
    unsigned int lp = (unsigned int)f2bf(r0) | ((unsigned int)f2bf(r1) << 16);
    return make_uint2(hp, lp);
}

// async global->LDS, 16B per lane; LDS dest is wave-uniform base + lane*16
__device__ inline void gload16(const void* g, void* lds) {
    __builtin_amdgcn_global_load_lds(
        (const __attribute__((address_space(1))) unsigned int*)g,
        (__attribute__((address_space(3))) unsigned int*)lds, 16, 0, 0);
}

// ---------------- Fused prep: proj(R) | wfrag(WV) | pe --------------------
// blocks 0..31  : proj_kernel body (RWh = R @ WR + bR -> fp16)
// blocks 32..79 : wfrag body (split-bf16 W fragments, MFMA layout)
// block  80     : peProd[h] = prod_a (P[a]@WP + bP)[h]
__global__ __launch_bounds__(256) void prep_kernel(
    const float* __restrict__ R, const float* __restrict__ WR, const float* __restrict__ bR,
    _Float16* __restrict__ RWh,
    const float* __restrict__ WV, unsigned short* __restrict__ wf,
    const float* __restrict__ P, const float* __restrict__ WP, const float* __restrict__ bP,
    float* __restrict__ peProd) {
    const int bid = blockIdx.x;
    const int tid = threadIdx.x;

    if (bid < 32) {
        // ---- proj: 1000 rows of R @ WR + bR -> fp16
        const int lane = tid & 63;
        const int wave = tid >> 6;
        const int wavesPerGrid = 32 * 4;
        const int waveId = bid * 4 + wave;
        const float2 b2 = ((const float2*)bR)[lane];
        const float2* __restrict__ W2 = (const float2*)WR;
        for (int rowBase0 = waveId * 8; rowBase0 < NUM_R; rowBase0 += wavesPerGrid * 8) {
            const int rowBase = __builtin_amdgcn_readfirstlane(rowBase0);
            float2 acc[8];
#pragma unroll
            for (int r8 = 0; r8 < 8; ++r8) acc[r8] = make_float2(0.f, 0.f);
#pragma unroll 4
            for (int k4 = 0; k4 < DD / 4; ++k4) {
                float4 v[8];
#pragma unroll
                for (int r8 = 0; r8 < 8; ++r8)
                    v[r8] = ((const float4*)(R + (size_t)(rowBase + r8) * DD))[k4];
#pragma unroll
                for (int kk = 0; kk < 4; ++kk) {
                    float2 w = W2[(k4 * 4 + kk) * 64 + lane];
#pragma unroll
                    for (int r8 = 0; r8 < 8; ++r8) {
                        float vv = (kk == 0) ? v[r8].x : (kk == 1) ? v[r8].y : (kk == 2) ? v[r8].z : v[r8].w;
                        acc[r8].x += vv * w.x;
                        acc[r8].y += vv * w.y;
                    }
                }
            }
#pragma unroll
            for (int r8 = 0; r8 < 8; ++r8) {
                if (rowBase + r8 < NUM_R) {
                    half2v h;
                    h.x = (_Float16)(acc[r8].x + b2.x);
                    h.y = (_Float16)(acc[r8].y + b2.y);
                    *(half2v*)(RWh + (size_t)(rowBase + r8) * HH + lane * 2) = h;
                }
            }
        }
    } else if (bid < 80) {
        // ---- wfrag: wf[kstep(6)][ctile(8)][split(2)][lane(64)][j(8)]
        if (tid < 64) {
            const int wb = bid - 32;
            const int ks = wb >> 3;  // 0..5
            const int ct = wb & 7;   // 0..7
            const int l = tid;       // 0..63
            const int col = ct * 16 + (l & 15);
            const int k0 = ks * 32 + (l >> 4) * 8;
            unsigned short hi[8], lo[8];
#pragma unroll
            for (int j = 0; j < 8; ++j) {
                float v = WV[(size_t)(k0 + j) * HH + col];
                unsigned short h = f2bf(v);
                hi[j] = h;
                lo[j] = f2bf(v - bf2f(h));
            }
            size_t base = (size_t)(ks * 8 + ct) * 2 * 512;
#pragma unroll
            for (int j = 0; j < 8; ++j) wf[base + l * 8 + j] = hi[j];
#pragma unroll
            for (int j = 0; j < 8; ++j) wf[base + 512 + l * 8 + j] = lo[j];
        }
    } else {
        // ---- pe: peProd[h] = prod_a (P[a]@WP + bP)[h]
        if (tid < HH) {
            int h = tid;
            float prod = 1.0f;
            for (int a = 0; a < ARITY; ++a) {
                float acc = bP[h];
                for (int d = 0; d < DD; ++d) acc += P[a * DD + d] * WP[d * HH + h];
                prod *= acc;
            }
            peProd[h] = prod;
        }
    }
}

// ---------------- Counted-vmcnt pipelined MFMA GEMM --------------------------
// C(fp16) = A @ W + bias. 64-row tile, 4 waves (2 row-halves x 2 col-halves).
// A staged into 6 DISTINCT LDS slots (one per K-step) via global_load_lds,
// 3 steps ahead. B register-loads issued BEFORE the A-stage each iteration and
// consumed one iteration later, so in-order vmcnt waits (manual AND the
// compiler's auto B-waits) never drain the A pipeline. Per-step sync is
// {s_waitcnt vmcnt(N_counted); s_barrier} -- never vmcnt(0) until the tail.
__global__ __launch_bounds__(256, 3) void gemm_ring(const float* __restrict__ A,
                                                    const unsigned short* __restrict__ wf,
                                                    const float* __restrict__ bias,
                                                    _Float16* __restrict__ C, int M) {
    __shared__ float at6[6][2048];  // 6 slots x 8KB: [row(64)][chunk-swizzled 32 floats]

    const int tid = threadIdx.x;
    const int l = tid & 63;
    const int wv = tid >> 6;        // 0..3
    const int wr = wv >> 1;         // row half
    const int wc = wv & 1;          // col half
    const int blockRow = blockIdx.x * 64;

    // staging addresses: thread t covers LDS float offset t*4 (rows tid>>3),
    // source chunk pre-swizzled: chunk = (t&7) ^ (row&7)   (rule #21: swizzle
    // the SOURCE, keep LDS dest linear)
    const int srow = tid >> 3;
    const int schunk = (tid & 7) ^ (srow & 7);
    const float *sptr0, *sptr1;
    {
        int r0 = blockRow + srow;      if (r0 >= M) r0 = M - 1;
        int r1 = blockRow + 32 + srow; if (r1 >= M) r1 = M - 1;
        sptr0 = A + (size_t)r0 * DI + schunk * 4;
        sptr1 = A + (size_t)r1 * DI + schunk * 4;
    }

    // fragment ds_read offsets (floats), chunk-swizzled by row
    int aoff[2][2];
#pragma unroll
    for (int rt = 0; rt < 2; ++rt) {
        const int R = wr * 32 + rt * 16 + (l & 15);
        const int q = l >> 4;
#pragma unroll
        for (int k = 0; k < 2; ++k)
            aoff[rt][k] = R * 32 + (((2 * q + k) ^ (R & 7)) << 2);
    }

    f32x4 acc[2][4];
#pragma unroll
    for (int i = 0; i < 2; ++i)
#pragma unroll
        for (int j = 0; j < 4; ++j) acc[i][j] = (f32x4){0.f, 0.f, 0.f, 0.f};

    short8 bh[2][4], bl[2][4];  // double-buffered B fragments (compile-time idx)
    const unsigned short* bbase = wf + (size_t)(wc * 4) * 1024 + l * 8;

#define STAGE(ks)                                                   \
    do {                                                            \
        gload16(sptr0 + (ks) * 32, &at6[(ks)][wv * 256]);           \
        gload16(sptr1 + (ks) * 32, &at6[(ks)][1024 + wv * 256]);    \
    } while (0)

#define LOADB(buf, ks)                                                         \
    do {                                                                       \
        _Pragma("unroll") for (int ct = 0; ct < 4; ++ct) {                     \
            const unsigned short* bp = bbase + (size_t)((ks) * 8 + ct) * 1024; \
            bh[buf][ct] = *(const short8*)bp;                                  \
            bl[buf][ct] = *(const short8*)(bp + 512);                          \
        }                                                                      \
    } while (0)

#define WAITV(n) asm volatile("s_waitcnt vmcnt(" #n ")" ::: "memory")

#define COMPUTE(j)                                                             \
    do {                                                                       \
        __builtin_amdgcn_sched_barrier(0);                                     \
        short8 ah[2], al[2];                                                   \
        _Pragma("unroll") for (int rt = 0; rt < 2; ++rt) {                     \
            f32x4 v0 = *(const f32x4*)&at6[(j)][aoff[rt][0]];                  \
            f32x4 v1 = *(const f32x4*)&at6[(j)][aoff[rt][1]];                  \
            uint2 s0 = splitpair(v0.x, v0.y);                                  \
            uint2 s1 = splitpair(v0.z, v0.w);                                  \
            uint2 s2 = splitpair(v1.x, v1.y);                                  \
            uint2 s3 = splitpair(v1.z, v1.w);                                  \
            u32x4 hp = {s0.x, s1.x, s2.x, s3.x};                               \
            u32x4 lp = {s0.y, s1.y, s2.y, s3.y};                               \
            ah[rt] = __builtin_bit_cast(short8, hp);                           \
            al[rt] = __builtin_bit_cast(short8, lp);                           \
        }                                                                      \
        _Pragma("unroll") for (int ct = 0; ct < 4; ++ct) {                     \
            _Pragma("unroll") for (int rt = 0; rt < 2; ++rt) {                 \
                acc[rt][ct] = __builtin_amdgcn_mfma_f32_16x16x32_bf16(         \
                    ah[rt], bh[(j) & 1][ct], acc[rt][ct], 0, 0, 0);            \
                acc[rt][ct] = __builtin_amdgcn_mfma_f32_16x16x32_bf16(         \
                    ah[rt], bl[(j) & 1][ct], acc[rt][ct], 0, 0, 0);            \
                acc[rt][ct] = __builtin_amdgcn_mfma_f32_16x16x32_bf16(         \
                    al[rt], bh[(j) & 1][ct], acc[rt][ct], 0, 0, 0);            \
            }                                                                  \
        }                                                                      \
    } while (0)

    // Prologue: B(0) first (B always issued before A so in-order waits on B
    // never cover later A loads), then A(0..2) -- 3-deep A pipeline.
    LOADB(0, 0);
    STAGE(0);
    STAGE(1);
    STAGE(2);

    // Hand-computed counted waits {14,12,12,10,8,0}: each guarantees the
    // prefix through {A(j), B(j)} completed while leaving A(j+1..j+3) and
    // B(j+1) in flight. (Per-wave: A-step = 2 gloads, B-step = 8 loads.)
    LOADB(1, 1); STAGE(3);
    WAITV(14); __builtin_amdgcn_s_barrier(); COMPUTE(0);

    LOADB(0, 2); STAGE(4);
    WAITV(12); __builtin_amdgcn_s_barrier(); COMPUTE(1);

    LOADB(1, 3); STAGE(5);
    WAITV(12); __builtin_amdgcn_s_barrier(); COMPUTE(2);

    LOADB(0, 4);
    WAITV(10); __builtin_amdgcn_s_barrier(); COMPUTE(3);

    LOADB(1, 5);
    WAITV(8); __builtin_amdgcn_s_barrier(); COMPUTE(4);

    WAITV(0); __builtin_amdgcn_s_barrier(); COMPUTE(5);

#undef STAGE
#undef LOADB
#undef WAITV
#undef COMPUTE

    // epilogue: C[row][col] = fp16(acc + bias[col])  (col=l&15, row=(l>>4)*4+j)
#pragma unroll
    for (int ct = 0; ct < 4; ++ct) {
        int col = (wc * 4 + ct) * 16 + (l & 15);
        float b = bias[col];
#pragma unroll
        for (int rt = 0; rt < 2; ++rt) {
            int rbase = blockRow + wr * 32 + rt * 16 + (l >> 4) * 4;
#pragma unroll
            for (int j = 0; j < 4; ++j) {
                int row = rbase + j;
                if (row < M) C[(size_t)row * HH + col] = (_Float16)(acc[rt][ct][j] + b);
            }
        }
    }
}

// ---------------- Gather - product - neighbor-sum (fp16 tables) --------------
// out[b,h] = peProd[h] * sum_n RWh[r[b,n]][h] * prod_a VWh[e[a,b,n]][h]
__global__ __launch_bounds__(256) void gather_kernel(const int* __restrict__ r,
                                                     const int* __restrict__ e,
                                                     const _Float16* __restrict__ VWh,
                                                     const _Float16* __restrict__ RWh,
                                                     const float* __restrict__ peProd,
                                                     float* __restrict__ out) {
    __shared__ int rIdx[NN];
    __shared__ int eIdx[ARITY][NN];
    __shared__ float4 partial[3][16][2];

    const int b = blockIdx.x;
    const int tid = threadIdx.x;

    if (tid < NN) {
        rIdx[tid] = r[b * NN + tid];
    } else {
        int t = tid - NN;
        eIdx[t >> 6][t & 63] = e[(size_t)(t >> 6) * BB * NN + b * NN + (t & 63)];
    }
    __syncthreads();

    const int lane = tid & 63;
    const int wv = tid >> 6;    // 0..3
    const int q = lane >> 4;    // neighbor sub-slot 0..3
    const int ho = lane & 15;   // h-octet: h = ho*8 .. +8

    float acc8[8];
#pragma unroll
    for (int k = 0; k < 8; ++k) acc8[k] = 0.f;

#pragma unroll
    for (int it = 0; it < 4; ++it) {
        int n = it * 16 + wv * 4 + q;
        half8 rw = *(const half8*)(RWh + (size_t)rIdx[n] * HH + ho * 8);
        half8 v0 = *(const half8*)(VWh + (size_t)eIdx[0][n] * HH + ho * 8);
        half8 v1 = *(const half8*)(VWh + (size_t)eIdx[1][n] * HH + ho * 8);
        half8 v2 = *(const half8*)(VWh + (size_t)eIdx[2][n] * HH + ho * 8);
        half8 p = rw * v0;
        p = p * v1;
        p = p * v2;
#pragma unroll
        for (int k = 0; k < 8; ++k) acc8[k] += (float)p[k];
    }

    // combine the 4 neighbor sub-slots (lane quarters share ho)
#pragma unroll
    for (int k = 0; k < 8; ++k) {
        acc8[k] += __shfl_xor(acc8[k], 16);
        acc8[k] += __shfl_xor(acc8[k], 32);
    }

    if (wv > 0 && lane < 16) {
        partial[wv - 1][ho][0] = make_float4(acc8[0], acc8[1], acc8[2], acc8[3]);
        partial[wv - 1][ho][1] = make_float4(acc8[4], acc8[5], acc8[6], acc8[7]);
    }
    __syncthreads();
    if (wv == 0 && lane < 16) {
        float4 s0 = make_float4(acc8[0], acc8[1], acc8[2], acc8[3]);
        float4 s1 = make_float4(acc8[4], acc8[5], acc8[6], acc8[7]);
#pragma unroll
        for (int g = 0; g < 3; ++g) {
            float4 t0 = partial[g][ho][0], t1 = partial[g][ho][1];
            s0.x += t0.x; s0.y += t0.y; s0.z += t0.z; s0.w += t0.w;
            s1.x += t1.x; s1.y += t1.y; s1.z += t1.z; s1.w += t1.w;
        }
        float4 p0 = ((const float4*)peProd)[ho * 2];
        float4 p1 = ((const float4*)peProd)[ho * 2 + 1];
        ((float4*)(out + (size_t)b * HH))[ho * 2] =
            make_float4(s0.x * p0.x, s0.y * p0.y, s0.z * p0.z, s0.w * p0.w);
        ((float4*)(out + (size_t)b * HH))[ho * 2 + 1] =
            make_float4(s1.x * p1.x, s1.y * p1.y, s1.z * p1.z, s1.w * p1.w);
    }
}

// ---------------- Launch -----------------------------------------------------
extern "C" void kernel_launch(void* const* d_in, const int* in_sizes, int n_in,
                              void* d_out, int out_size, void* d_ws, size_t ws_size,
                              hipStream_t stream) {
    const int* r = (const int*)d_in[0];
    const int* e = (const int*)d_in[1];
    const float* V = (const float*)d_in[2];
    const float* R = (const float*)d_in[3];
    const float* P = (const float*)d_in[4];
    const float* WV = (const float*)d_in[5];
    const float* bV = (const float*)d_in[6];
    const float* WR = (const float*)d_in[7];
    const float* bR = (const float*)d_in[8];
    const float* WP = (const float*)d_in[9];
    const float* bP = (const float*)d_in[10];
    float* out = (float*)d_out;

    // ws layout: VWh [NUM_V,H] fp16 | RWh [NUM_R,H] fp16 | peProd [H] f32 | Wfrag 96 KB
    _Float16* VWh = (_Float16*)d_ws;
    _Float16* RWh = VWh + (size_t)NUM_V * HH;
    float* peProd = (float*)(RWh + (size_t)NUM_R * HH);
    unsigned short* wfrag = (unsigned short*)(peProd + HH);

    prep_kernel<<<81, 256, 0, stream>>>(R, WR, bR, RWh, WV, wfrag, P, WP, bP, peProd);
    gemm_ring<<<(NUM_V + 63) / 64, 256, 0, stream>>>(V, wfrag, bV, VWh, NUM_V);
    gather_kernel<<<BB, 256, 0, stream>>>(r, e, VWh, RWh, peProd, out);
}

// Round 3
// 85.130 us; speedup vs baseline: 1.1951x; 1.0069x over previous
//
#include <hip/hip_runtime.h>

#define NUM_V 100000
#define NUM_R 1000
#define ARITY 3
#define DD 128
#define DI 192   /* D + I */
#define HH 128
#define BB 4096
#define NN 64

typedef __attribute__((ext_vector_type(8))) short short8;
typedef __attribute__((ext_vector_type(4))) float f32x4;
typedef __attribute__((ext_vector_type(4))) unsigned int u32x4;
typedef __attribute__((ext_vector_type(8))) _Float16 half8;
typedef __attribute__((ext_vector_type(2))) _Float16 half2v;

__device__ inline unsigned short f2bf(float f) {
    unsigned int u = __float_as_uint(f);
    unsigned int r = (u + 0x7fffu + ((u >> 16) & 1u)) >> 16;
    return (unsigned short)r;
}
__device__ inline float bf2f(unsigned short s) {
    return __uint_as_float(((unsigned int)s) << 16);
}

// split pair (f0,f1) -> {hi: packed truncated bf16 pair, lo: packed RNE bf16 of residual}
__device__ inline uint2 splitpair(float f0, float f1) {
    unsigned int u0 = __float_as_uint(f0), u1 = __float_as_uint(f1);
    unsigned int hp = __builtin_amdgcn_perm(u1, u0, 0x07060302u);  // {u0.hi16, u1.hi16}
    float r0 = f0 - __uint_as_float(u0 & 0xffff0000u);
    float r1 = f1 - __uint_as_float(u1 & 0xffff0000u);
    unsigned int lp = (unsigned int)f2bf(r0) | ((unsigned int)f2bf(r1) << 16);
    return make_uint2(hp, lp);
}

// async global->LDS, 16B per lane; LDS dest is wave-uniform base + lane*16
__device__ inline void gload16(const void* g, void* lds) {
    __builtin_amdgcn_global_load_lds(
        (const __attribute__((address_space(1))) unsigned int*)g,
        (__attribute__((address_space(3))) unsigned int*)lds, 16, 0, 0);
}

// ---------------- Fused prep: proj(R) | wfrag(WV) | pe --------------------
// blocks 0..31  : proj body (RWh = R @ WR + bR -> fp16)
// blocks 32..79 : wfrag body (split-bf16 W fragments, MFMA layout)
// block  80     : peProd[h] = prod_a (P[a]@WP + bP)[h]
__global__ __launch_bounds__(256) void prep_kernel(
    const float* __restrict__ R, const float* __restrict__ WR, const float* __restrict__ bR,
    _Float16* __restrict__ RWh,
    const float* __restrict__ WV, unsigned short* __restrict__ wf,
    const float* __restrict__ P, const float* __restrict__ WP, const float* __restrict__ bP,
    float* __restrict__ peProd) {
    const int bid = blockIdx.x;
    const int tid = threadIdx.x;

    if (bid < 32) {
        const int lane = tid & 63;
        const int wave = tid >> 6;
        const int wavesPerGrid = 32 * 4;
        const int waveId = bid * 4 + wave;
        const float2 b2 = ((const float2*)bR)[lane];
        const float2* __restrict__ W2 = (const float2*)WR;
        for (int rowBase0 = waveId * 8; rowBase0 < NUM_R; rowBase0 += wavesPerGrid * 8) {
            const int rowBase = __builtin_amdgcn_readfirstlane(rowBase0);
            float2 acc[8];
#pragma unroll
            for (int r8 = 0; r8 < 8; ++r8) acc[r8] = make_float2(0.f, 0.f);
#pragma unroll 4
            for (int k4 = 0; k4 < DD / 4; ++k4) {
                float4 v[8];
#pragma unroll
                for (int r8 = 0; r8 < 8; ++r8)
                    v[r8] = ((const float4*)(R + (size_t)(rowBase + r8) * DD))[k4];
#pragma unroll
                for (int kk = 0; kk < 4; ++kk) {
                    float2 w = W2[(k4 * 4 + kk) * 64 + lane];
#pragma unroll
                    for (int r8 = 0; r8 < 8; ++r8) {
                        float vv = (kk == 0) ? v[r8].x : (kk == 1) ? v[r8].y : (kk == 2) ? v[r8].z : v[r8].w;
                        acc[r8].x += vv * w.x;
                        acc[r8].y += vv * w.y;
                    }
                }
            }
#pragma unroll
            for (int r8 = 0; r8 < 8; ++r8) {
                if (rowBase + r8 < NUM_R) {
                    half2v h;
                    h.x = (_Float16)(acc[r8].x + b2.x);
                    h.y = (_Float16)(acc[r8].y + b2.y);
                    *(half2v*)(RWh + (size_t)(rowBase + r8) * HH + lane * 2) = h;
                }
            }
        }
    } else if (bid < 80) {
        if (tid < 64) {
            const int wb = bid - 32;
            const int ks = wb >> 3;  // 0..5
            const int ct = wb & 7;   // 0..7
            const int l = tid;       // 0..63
            const int col = ct * 16 + (l & 15);
            const int k0 = ks * 32 + (l >> 4) * 8;
            unsigned short hi[8], lo[8];
#pragma unroll
            for (int j = 0; j < 8; ++j) {
                float v = WV[(size_t)(k0 + j) * HH + col];
                unsigned short h = f2bf(v);
                hi[j] = h;
                lo[j] = f2bf(v - bf2f(h));
            }
            size_t base = (size_t)(ks * 8 + ct) * 2 * 512;
#pragma unroll
            for (int j = 0; j < 8; ++j) wf[base + l * 8 + j] = hi[j];
#pragma unroll
            for (int j = 0; j < 8; ++j) wf[base + 512 + l * 8 + j] = lo[j];
        }
    } else {
        if (tid < HH) {
            int h = tid;
            float prod = 1.0f;
            for (int a = 0; a < ARITY; ++a) {
                float acc = bP[h];
                for (int d = 0; d < DD; ++d) acc += P[a * DD + d] * WP[d * HH + h];
                prod *= acc;
            }
            peProd[h] = prod;
        }
    }
}

// ---------------- Occupancy-first pipelined MFMA GEMM ------------------------
// C(fp16) = A @ W + bias. 32-row tile, 4 waves each owning a 32x32 output
// quarter (col quarter wv). A staged into 6 distinct 4KB LDS slots via
// global_load_lds (1 instr/wave/step), 3 steps ahead; B register-loads
// (4/wave/step) issued before the A-stage; counted vmcnt waits (permutation-
// robust {5,5,5,5,4,0}) + raw s_barrier per step. 24KB LDS + <=85 VGPR ->
// 6 blocks/CU (24 waves, 75% occupancy): latency hiding comes from TLP
// across blocks (Guideline 1), not just the in-block pipeline.
__global__ __launch_bounds__(256, 6) void gemm_ring(const float* __restrict__ A,
                                                    const unsigned short* __restrict__ wf,
                                                    const float* __restrict__ bias,
                                                    _Float16* __restrict__ C, int M) {
    __shared__ float at6[6][1024];  // 6 slots x 4KB: [row(32)][chunk-swizzled 32 floats]

    const int tid = threadIdx.x;
    const int l = tid & 63;
    const int wv = tid >> 6;        // 0..3 = col quarter
    const int blockRow = blockIdx.x * 32;

    // staging: wave wv stages rows wv*8 .. wv*8+8 of the 32-row tile.
    // LDS dest linear (wave base + lane*16); source chunk pre-swizzled
    // (rule #21): chunk = (l&7) ^ (localrow&7), localrow = l>>3.
    const float* sptr;
    {
        int lr = (wv << 3) + (l >> 3);              // 0..31 local row
        int rr = blockRow + lr; if (rr >= M) rr = M - 1;
        int schunk = (l & 7) ^ (l >> 3);            // (localrow&7) == l>>3 here
        sptr = A + (size_t)rr * DI + schunk * 4;
    }

    // fragment ds_read offsets (floats), chunk-swizzled by row
    int aoff[2][2];
#pragma unroll
    for (int rt = 0; rt < 2; ++rt) {
        const int R = rt * 16 + (l & 15);
        const int q = l >> 4;
#pragma unroll
        for (int k = 0; k < 2; ++k)
            aoff[rt][k] = R * 32 + (((2 * q + k) ^ (R & 7)) << 2);
    }

    f32x4 acc[2][2];
#pragma unroll
    for (int i = 0; i < 2; ++i)
#pragma unroll
        for (int j = 0; j < 2; ++j) acc[i][j] = (f32x4){0.f, 0.f, 0.f, 0.f};

    short8 bh[2][2], bl[2][2];  // double-buffered B fragments (compile-time idx)
    const unsigned short* bbase = wf + (size_t)(wv * 2) * 1024 + l * 8;

#define STAGE(ks) gload16(sptr + (ks) * 32, &at6[(ks)][wv * 256])

#define LOADB(buf, ks)                                                         \
    do {                                                                       \
        _Pragma("unroll") for (int ct = 0; ct < 2; ++ct) {                     \
            const unsigned short* bp = bbase + (size_t)((ks) * 8 + ct) * 1024; \
            bh[buf][ct] = *(const short8*)bp;                                  \
            bl[buf][ct] = *(const short8*)(bp + 512);                          \
        }                                                                      \
    } while (0)

#define WAITV(n) asm volatile("s_waitcnt vmcnt(" #n ")" ::: "memory")

#define COMPUTE(j)                                                             \
    do {                                                                       \
        __builtin_amdgcn_sched_barrier(0);                                     \
        short8 ah[2], al[2];                                                   \
        _Pragma("unroll") for (int rt = 0; rt < 2; ++rt) {                     \
            f32x4 v0 = *(const f32x4*)&at6[(j)][aoff[rt][0]];                  \
            f32x4 v1 = *(const f32x4*)&at6[(j)][aoff[rt][1]];                  \
            uint2 s0 = splitpair(v0.x, v0.y);                                  \
            uint2 s1 = splitpair(v0.z, v0.w);                                  \
            uint2 s2 = splitpair(v1.x, v1.y);                                  \
            uint2 s3 = splitpair(v1.z, v1.w);                                  \
            u32x4 hp = {s0.x, s1.x, s2.x, s3.x};                               \
            u32x4 lp = {s0.y, s1.y, s2.y, s3.y};                               \
            ah[rt] = __builtin_bit_cast(short8, hp);                           \
            al[rt] = __builtin_bit_cast(short8, lp);                           \
        }                                                                      \
        _Pragma("unroll") for (int ct = 0; ct < 2; ++ct) {                     \
            _Pragma("unroll") for (int rt = 0; rt < 2; ++rt) {                 \
                acc[rt][ct] = __builtin_amdgcn_mfma_f32_16x16x32_bf16(         \
                    ah[rt], bh[(j) & 1][ct], acc[rt][ct], 0, 0, 0);            \
                acc[rt][ct] = __builtin_amdgcn_mfma_f32_16x16x32_bf16(         \
                    ah[rt], bl[(j) & 1][ct], acc[rt][ct], 0, 0, 0);            \
                acc[rt][ct] = __builtin_amdgcn_mfma_f32_16x16x32_bf16(         \
                    al[rt], bh[(j) & 1][ct], acc[rt][ct], 0, 0, 0);            \
            }                                                                  \
        }                                                                      \
    } while (0)

    // Prologue: B(0) first, then A(0..2) -- 3-deep A pipeline.
    LOADB(0, 0);
    STAGE(0);
    STAGE(1);
    STAGE(2);

    // Permutation-robust counted waits: each leaves the newest region
    // (4 B-loads + 1 A-stage) in flight while guaranteeing {A(j), B(j)} done.
    LOADB(1, 1); STAGE(3);
    WAITV(5); __builtin_amdgcn_s_barrier(); COMPUTE(0);

    LOADB(0, 2); STAGE(4);
    WAITV(5); __builtin_amdgcn_s_barrier(); COMPUTE(1);

    LOADB(1, 3); STAGE(5);
    WAITV(5); __builtin_amdgcn_s_barrier(); COMPUTE(2);

    LOADB(0, 4);
    WAITV(5); __builtin_amdgcn_s_barrier(); COMPUTE(3);

    LOADB(1, 5);
    WAITV(4); __builtin_amdgcn_s_barrier(); COMPUTE(4);

    WAITV(0); __builtin_amdgcn_s_barrier(); COMPUTE(5);

#undef STAGE
#undef LOADB
#undef WAITV
#undef COMPUTE

    // epilogue: C[row][col] = fp16(acc + bias[col])  (col=l&15, row=(l>>4)*4+j)
#pragma unroll
    for (int ct = 0; ct < 2; ++ct) {
        int col = (wv * 2 + ct) * 16 + (l & 15);
        float b = bias[col];
#pragma unroll
        for (int rt = 0; rt < 2; ++rt) {
            int rbase = blockRow + rt * 16 + (l >> 4) * 4;
#pragma unroll
            for (int j = 0; j < 4; ++j) {
                int row = rbase + j;
                if (row < M) C[(size_t)row * HH + col] = (_Float16)(acc[rt][ct][j] + b);
            }
        }
    }
}

// ---------------- Gather - product - neighbor-sum (fp16 tables) --------------
// out[b,h] = peProd[h] * sum_n RWh[r[b,n]][h] * prod_a VWh[e[a,b,n]][h]
__global__ __launch_bounds__(256) void gather_kernel(const int* __restrict__ r,
                                                     const int* __restrict__ e,
                                                     const _Float16* __restrict__ VWh,
                                                     const _Float16* __restrict__ RWh,
                                                     const float* __restrict__ peProd,
                                                     float* __restrict__ out) {
    __shared__ int rIdx[NN];
    __shared__ int eIdx[ARITY][NN];
    __shared__ float4 partial[3][16][2];

    const int b = blockIdx.x;
    const int tid = threadIdx.x;

    if (tid < NN) {
        rIdx[tid] = r[b * NN + tid];
    } else {
        int t = tid - NN;
        eIdx[t >> 6][t & 63] = e[(size_t)(t >> 6) * BB * NN + b * NN + (t & 63)];
    }
    __syncthreads();

    const int lane = tid & 63;
    const int wv = tid >> 6;    // 0..3
    const int q = lane >> 4;    // neighbor sub-slot 0..3
    const int ho = lane & 15;   // h-octet: h = ho*8 .. +8

    float acc8[8];
#pragma unroll
    for (int k = 0; k < 8; ++k) acc8[k] = 0.f;

#pragma unroll
    for (int it = 0; it < 4; ++it) {
        int n = it * 16 + wv * 4 + q;
        half8 rw = *(const half8*)(RWh + (size_t)rIdx[n] * HH + ho * 8);
        half8 v0 = *(const half8*)(VWh + (size_t)eIdx[0][n] * HH + ho * 8);
        half8 v1 = *(const half8*)(VWh + (size_t)eIdx[1][n] * HH + ho * 8);
        half8 v2 = *(const half8*)(VWh + (size_t)eIdx[2][n] * HH + ho * 8);
        half8 p = rw * v0;
        p = p * v1;
        p = p * v2;
#pragma unroll
        for (int k = 0; k < 8; ++k) acc8[k] += (float)p[k];
    }

    // combine the 4 neighbor sub-slots (lane quarters share ho)
#pragma unroll
    for (int k = 0; k < 8; ++k) {
        acc8[k] += __shfl_xor(acc8[k], 16);
        acc8[k] += __shfl_xor(acc8[k], 32);
    }

    if (wv > 0 && lane < 16) {
        partial[wv - 1][ho][0] = make_float4(acc8[0], acc8[1], acc8[2], acc8[3]);
        partial[wv - 1][ho][1] = make_float4(acc8[4], acc8[5], acc8[6], acc8[7]);
    }
    __syncthreads();
    if (wv == 0 && lane < 16) {
        float4 s0 = make_float4(acc8[0], acc8[1], acc8[2], acc8[3]);
        float4 s1 = make_float4(acc8[4], acc8[5], acc8[6], acc8[7]);
#pragma unroll
        for (int g = 0; g < 3; ++g) {
            float4 t0 = partial[g][ho][0], t1 = partial[g][ho][1];
            s0.x += t0.x; s0.y += t0.y; s0.z += t0.z; s0.w += t0.w;
            s1.x += t1.x; s1.y += t1.y; s1.z += t1.z; s1.w += t1.w;
        }
        float4 p0 = ((const float4*)peProd)[ho * 2];
        float4 p1 = ((const float4*)peProd)[ho * 2 + 1];
        ((float4*)(out + (size_t)b * HH))[ho * 2] =
            make_float4(s0.x * p0.x, s0.y * p0.y, s0.z * p0.z, s0.w * p0.w);
        ((float4*)(out + (size_t)b * HH))[ho * 2 + 1] =
            make_float4(s1.x * p1.x, s1.y * p1.y, s1.z * p1.z, s1.w * p1.w);
    }
}

// ---------------- Launch -----------------------------------------------------
extern "C" void kernel_launch(void* const* d_in, const int* in_sizes, int n_in,
                              void* d_out, int out_size, void* d_ws, size_t ws_size,
                              hipStream_t stream) {
    const int* r = (const int*)d_in[0];
    const int* e = (const int*)d_in[1];
    const float* V = (const float*)d_in[2];
    const float* R = (const float*)d_in[3];
    const float* P = (const float*)d_in[4];
    const float* WV = (const float*)d_in[5];
    const float* bV = (const float*)d_in[6];
    const float* WR = (const float*)d_in[7];
    const float* bR = (const float*)d_in[8];
    const float* WP = (const float*)d_in[9];
    const float* bP = (const float*)d_in[10];
    float* out = (float*)d_out;

    // ws layout: VWh [NUM_V,H] fp16 | RWh [NUM_R,H] fp16 | peProd [H] f32 | Wfrag 96 KB
    _Float16* VWh = (_Float16*)d_ws;
    _Float16* RWh = VWh + (size_t)NUM_V * HH;
    float* peProd = (float*)(RWh + (size_t)NUM_R * HH);
    unsigned short* wfrag = (unsigned short*)(peProd + HH);

    prep_kernel<<<81, 256, 0, stream>>>(R, WR, bR, RWh, WV, wfrag, P, WP, bP, peProd);
    gemm_ring<<<(NUM_V + 31) / 32, 256, 0, stream>>>(V, wfrag, bV, VWh, NUM_V);
    gather_kernel<<<BB, 256, 0, stream>>>(r, e, VWh, RWh, peProd, out);
}

// Round 4
// 82.834 us; speedup vs baseline: 1.2282x; 1.0277x over previous
//
#include <hip/hip_runtime.h>

#define NUM_V 100000
#define NUM_R 1000
#define ARITY 3
#define DD 128
#define DI 192   /* D + I */
#define HH 128
#define BB 4096
#define NN 64

typedef __attribute__((ext_vector_type(8))) short short8;
typedef __attribute__((ext_vector_type(4))) float f32x4;
typedef __attribute__((ext_vector_type(4))) unsigned int u32x4;
typedef __attribute__((ext_vector_type(8))) _Float16 half8;
typedef __attribute__((ext_vector_type(2))) _Float16 half2v;

__device__ inline unsigned short f2bf(float f) {
    unsigned int u = __float_as_uint(f);
    unsigned int r = (u + 0x7fffu + ((u >> 16) & 1u)) >> 16;
    return (unsigned short)r;
}
__device__ inline float bf2f(unsigned short s) {
    return __uint_as_float(((unsigned int)s) << 16);
}

// split pair (f0,f1) -> {hi: packed truncated bf16 pair, lo: packed RNE bf16 of residual}
__device__ inline uint2 splitpair(float f0, float f1) {
    unsigned int u0 = __float_as_uint(f0), u1 = __float_as_uint(f1);
    unsigned int hp = __builtin_amdgcn_perm(u1, u0, 0x07060302u);  // {u0.hi16, u1.hi16}
    float r0 = f0 - __uint_as_float(u0 & 0xffff0000u);
    float r1 = f1 - __uint_as_float(u1 & 0xffff0000u);
    unsigned int lp = (unsigned int)f2bf(r0) | ((unsigned int)f2bf(r1) << 16);
    return make_uint2(hp, lp);
}

// async global->LDS, 16B per lane; LDS dest is wave-uniform base + lane*16
__device__ inline void gload16(const void* g, void* lds) {
    __builtin_amdgcn_global_load_lds(
        (const __attribute__((address_space(1))) unsigned int*)g,
        (__attribute__((address_space(3))) unsigned int*)lds, 16, 0, 0);
}

// ---------------- Fused prep: proj(R) | wfrag(WV) | pe --------------------
// blocks 0..31  : proj body (RWh = R @ WR + bR -> fp16)
// blocks 32..79 : wfrag body (split-bf16 W fragments, MFMA layout)
// block  80     : peProd[h] = prod_a (P[a]@WP + bP)[h]
__global__ __launch_bounds__(256) void prep_kernel(
    const float* __restrict__ R, const float* __restrict__ WR, const float* __restrict__ bR,
    _Float16* __restrict__ RWh,
    const float* __restrict__ WV, unsigned short* __restrict__ wf,
    const float* __restrict__ P, const float* __restrict__ WP, const float* __restrict__ bP,
    float* __restrict__ peProd) {
    const int bid = blockIdx.x;
    const int tid = threadIdx.x;

    if (bid < 32) {
        const int lane = tid & 63;
        const int wave = tid >> 6;
        const int wavesPerGrid = 32 * 4;
        const int waveId = bid * 4 + wave;
        const float2 b2 = ((const float2*)bR)[lane];
        const float2* __restrict__ W2 = (const float2*)WR;
        for (int rowBase0 = waveId * 8; rowBase0 < NUM_R; rowBase0 += wavesPerGrid * 8) {
            const int rowBase = __builtin_amdgcn_readfirstlane(rowBase0);
            float2 acc[8];
#pragma unroll
            for (int r8 = 0; r8 < 8; ++r8) acc[r8] = make_float2(0.f, 0.f);
#pragma unroll 4
            for (int k4 = 0; k4 < DD / 4; ++k4) {
                float4 v[8];
#pragma unroll
                for (int r8 = 0; r8 < 8; ++r8)
                    v[r8] = ((const float4*)(R + (size_t)(rowBase + r8) * DD))[k4];
#pragma unroll
                for (int kk = 0; kk < 4; ++kk) {
                    float2 w = W2[(k4 * 4 + kk) * 64 + lane];
#pragma unroll
                    for (int r8 = 0; r8 < 8; ++r8) {
                        float vv = (kk == 0) ? v[r8].x : (kk == 1) ? v[r8].y : (kk == 2) ? v[r8].z : v[r8].w;
                        acc[r8].x += vv * w.x;
                        acc[r8].y += vv * w.y;
                    }
                }
            }
#pragma unroll
            for (int r8 = 0; r8 < 8; ++r8) {
                if (rowBase + r8 < NUM_R) {
                    half2v h;
                    h.x = (_Float16)(acc[r8].x + b2.x);
                    h.y = (_Float16)(acc[r8].y + b2.y);
                    *(half2v*)(RWh + (size_t)(rowBase + r8) * HH + lane * 2) = h;
                }
            }
        }
    } else if (bid < 80) {
        if (tid < 64) {
            const int wb = bid - 32;
            const int ks = wb >> 3;  // 0..5
            const int ct = wb & 7;   // 0..7
            const int l = tid;       // 0..63
            const int col = ct * 16 + (l & 15);
            const int k0 = ks * 32 + (l >> 4) * 8;
            unsigned short hi[8], lo[8];
#pragma unroll
            for (int j = 0; j < 8; ++j) {
                float v = WV[(size_t)(k0 + j) * HH + col];
                unsigned short h = f2bf(v);
                hi[j] = h;
                lo[j] = f2bf(v - bf2f(h));
            }
            size_t base = (size_t)(ks * 8 + ct) * 2 * 512;
#pragma unroll
            for (int j = 0; j < 8; ++j) wf[base + l * 8 + j] = hi[j];
#pragma unroll
            for (int j = 0; j < 8; ++j) wf[base + 512 + l * 8 + j] = lo[j];
        }
    } else {
        if (tid < HH) {
            int h = tid;
            float prod = 1.0f;
            for (int a = 0; a < ARITY; ++a) {
                float acc = bP[h];
                for (int d = 0; d < DD; ++d) acc += P[a * DD + d] * WP[d * HH + h];
                prod *= acc;
            }
            peProd[h] = prod;
        }
    }
}

// ---------------- B-resident MFMA GEMM (one barrier, no choreography) --------
// C(fp16) = A @ W + bias. The ENTIRE split-bf16 W-fragment table (96 KB) is
// staged into LDS once per block; thereafter the main loop has ZERO barriers
// and ZERO global B-traffic. 768 threads = 12 waves, each wave owns exactly
// one 32x128 output tile (M = 3125 * 32 exactly). A is register-prefetched
// 2-deep over the 6 K-steps; all waits are compiler-counted lgkm/vmcnt on
// straight-line code. One wave writes entire 256B C-lines (write-combining).
__global__ __launch_bounds__(768, 3) void gemm_bres(const float* __restrict__ A,
                                                    const unsigned short* __restrict__ wf,
                                                    const float* __restrict__ bias,
                                                    _Float16* __restrict__ C, int M) {
    __shared__ unsigned short bsm[49152];  // 96 KB, byte-identical to wfrag layout

    const int tid = threadIdx.x;
    const int l = tid & 63;
    const int wv = tid >> 6;  // 0..11

    // ---- stage full wfrag: 12 waves x 8 x (64 lanes x 16B) = 96 KB, linear
#pragma unroll
    for (int i = 0; i < 8; ++i) {
        const int off = i * 12288 + wv * 1024;  // bytes, wave-uniform dest
        gload16((const char*)wf + off + l * 16, (char*)bsm + off);
    }

    const int tile = blockIdx.x * 12 + wv;  // 32-row tile id
    const int rowbase = tile * 32;
    const bool active = rowbase < M;  // wave-uniform

    // bias per col-tile
    float bcol[8];
#pragma unroll
    for (int ct = 0; ct < 8; ++ct) bcol[ct] = bias[ct * 16 + (l & 15)];

    // A fragment pointers: row = rowbase + rt*16 + (l&15), k-base (l>>4)*8
    const float* aptr[2];
#pragma unroll
    for (int rt = 0; rt < 2; ++rt) {
        int rr = rowbase + rt * 16 + (l & 15);
        if (rr >= M) rr = M - 1;
        aptr[rt] = A + (size_t)rr * DI + (l >> 4) * 8;
    }

    f32x4 acc[2][8];
#pragma unroll
    for (int rt = 0; rt < 2; ++rt)
#pragma unroll
        for (int ct = 0; ct < 8; ++ct) acc[rt][ct] = (f32x4){0.f, 0.f, 0.f, 0.f};

    float4 va[2][2][2];  // [buf][rt][half]
#define LOAD_A(buf, ks)                                               \
    _Pragma("unroll") for (int rt = 0; rt < 2; ++rt) {                \
        va[buf][rt][0] = *(const float4*)(aptr[rt] + (ks) * 32);      \
        va[buf][rt][1] = *(const float4*)(aptr[rt] + (ks) * 32 + 4);  \
    }

    if (active) { LOAD_A(0, 0) }

    __syncthreads();  // the ONLY barrier: publishes LDS B-table to all waves
    if (!active) return;

#pragma unroll
    for (int ks = 0; ks < 6; ++ks) {
        const int cur = ks & 1;
        if (ks < 5) { LOAD_A(cur ^ 1, ks + 1) }

        // split-bf16 convert of the current A fragments
        short8 ah[2], al[2];
#pragma unroll
        for (int rt = 0; rt < 2; ++rt) {
            uint2 s0 = splitpair(va[cur][rt][0].x, va[cur][rt][0].y);
            uint2 s1 = splitpair(va[cur][rt][0].z, va[cur][rt][0].w);
            uint2 s2 = splitpair(va[cur][rt][1].x, va[cur][rt][1].y);
            uint2 s3 = splitpair(va[cur][rt][1].z, va[cur][rt][1].w);
            u32x4 hp = {s0.x, s1.x, s2.x, s3.x};
            u32x4 lp = {s0.y, s1.y, s2.y, s3.y};
            ah[rt] = __builtin_bit_cast(short8, hp);
            al[rt] = __builtin_bit_cast(short8, lp);
        }

#pragma unroll
        for (int ct = 0; ct < 8; ++ct) {
            const int fb = (ks * 8 + ct) * 1024;  // ushort index of fragment
            short8 bh = *(const short8*)&bsm[fb + l * 8];
            short8 bl = *(const short8*)&bsm[fb + 512 + l * 8];
#pragma unroll
            for (int rt = 0; rt < 2; ++rt) {
                acc[rt][ct] = __builtin_amdgcn_mfma_f32_16x16x32_bf16(ah[rt], bh, acc[rt][ct], 0, 0, 0);
                acc[rt][ct] = __builtin_amdgcn_mfma_f32_16x16x32_bf16(ah[rt], bl, acc[rt][ct], 0, 0, 0);
                acc[rt][ct] = __builtin_amdgcn_mfma_f32_16x16x32_bf16(al[rt], bh, acc[rt][ct], 0, 0, 0);
            }
        }
    }
#undef LOAD_A

    // epilogue: one wave writes full 256B C-lines (col=ct*16+(l&15))
#pragma unroll
    for (int rt = 0; rt < 2; ++rt) {
        const int rb = rowbase + rt * 16 + (l >> 4) * 4;
#pragma unroll
        for (int j = 0; j < 4; ++j) {
            const int row = rb + j;
            if (row < M) {
#pragma unroll
                for (int ct = 0; ct < 8; ++ct)
                    C[(size_t)row * HH + ct * 16 + (l & 15)] = (_Float16)(acc[rt][ct][j] + bcol[ct]);
            }
        }
    }
}

// ---------------- Gather - product - neighbor-sum (fp16 tables) --------------
// out[b,h] = peProd[h] * sum_n RWh[r[b,n]][h] * prod_a VWh[e[a,b,n]][h]
__global__ __launch_bounds__(256) void gather_kernel(const int* __restrict__ r,
                                                     const int* __restrict__ e,
                                                     const _Float16* __restrict__ VWh,
                                                     const _Float16* __restrict__ RWh,
                                                     const float* __restrict__ peProd,
                                                     float* __restrict__ out) {
    __shared__ int rIdx[NN];
    __shared__ int eIdx[ARITY][NN];
    __shared__ float4 partial[3][16][2];

    const int b = blockIdx.x;
    const int tid = threadIdx.x;

    if (tid < NN) {
        rIdx[tid] = r[b * NN + tid];
    } else {
        int t = tid - NN;
        eIdx[t >> 6][t & 63] = e[(size_t)(t >> 6) * BB * NN + b * NN + (t & 63)];
    }
    __syncthreads();

    const int lane = tid & 63;
    const int wv = tid >> 6;    // 0..3
    const int q = lane >> 4;    // neighbor sub-slot 0..3
    const int ho = lane & 15;   // h-octet: h = ho*8 .. +8

    float acc8[8];
#pragma unroll
    for (int k = 0; k < 8; ++k) acc8[k] = 0.f;

#pragma unroll
    for (int it = 0; it < 4; ++it) {
        int n = it * 16 + wv * 4 + q;
        half8 rw = *(const half8*)(RWh + (size_t)rIdx[n] * HH + ho * 8);
        half8 v0 = *(const half8*)(VWh + (size_t)eIdx[0][n] * HH + ho * 8);
        half8 v1 = *(const half8*)(VWh + (size_t)eIdx[1][n] * HH + ho * 8);
        half8 v2 = *(const half8*)(VWh + (size_t)eIdx[2][n] * HH + ho * 8);
        half8 p = rw * v0;
        p = p * v1;
        p = p * v2;
#pragma unroll
        for (int k = 0; k < 8; ++k) acc8[k] += (float)p[k];
    }

    // combine the 4 neighbor sub-slots (lane quarters share ho)
#pragma unroll
    for (int k = 0; k < 8; ++k) {
        acc8[k] += __shfl_xor(acc8[k], 16);
        acc8[k] += __shfl_xor(acc8[k], 32);
    }

    if (wv > 0 && lane < 16) {
        partial[wv - 1][ho][0] = make_float4(acc8[0], acc8[1], acc8[2], acc8[3]);
        partial[wv - 1][ho][1] = make_float4(acc8[4], acc8[5], acc8[6], acc8[7]);
    }
    __syncthreads();
    if (wv == 0 && lane < 16) {
        float4 s0 = make_float4(acc8[0], acc8[1], acc8[2], acc8[3]);
        float4 s1 = make_float4(acc8[4], acc8[5], acc8[6], acc8[7]);
#pragma unroll
        for (int g = 0; g < 3; ++g) {
            float4 t0 = partial[g][ho][0], t1 = partial[g][ho][1];
            s0.x += t0.x; s0.y += t0.y; s0.z += t0.z; s0.w += t0.w;
            s1.x += t1.x; s1.y += t1.y; s1.z += t1.z; s1.w += t1.w;
        }
        float4 p0 = ((const float4*)peProd)[ho * 2];
        float4 p1 = ((const float4*)peProd)[ho * 2 + 1];
        ((float4*)(out + (size_t)b * HH))[ho * 2] =
            make_float4(s0.x * p0.x, s0.y * p0.y, s0.z * p0.z, s0.w * p0.w);
        ((float4*)(out + (size_t)b * HH))[ho * 2 + 1] =
            make_float4(s1.x * p1.x, s1.y * p1.y, s1.z * p1.z, s1.w * p1.w);
    }
}

// ---------------- Launch -----------------------------------------------------
extern "C" void kernel_launch(void* const* d_in, const int* in_sizes, int n_in,
                              void* d_out, int out_size, void* d_ws, size_t ws_size,
                              hipStream_t stream) {
    const int* r = (const int*)d_in[0];
    const int* e = (const int*)d_in[1];
    const float* V = (const float*)d_in[2];
    const float* R = (const float*)d_in[3];
    const float* P = (const float*)d_in[4];
    const float* WV = (const float*)d_in[5];
    const float* bV = (const float*)d_in[6];
    const float* WR = (const float*)d_in[7];
    const float* bR = (const float*)d_in[8];
    const float* WP = (const float*)d_in[9];
    const float* bP = (const float*)d_in[10];
    float* out = (float*)d_out;

    // ws layout: VWh [NUM_V,H] fp16 | RWh [NUM_R,H] fp16 | peProd [H] f32 | Wfrag 96 KB
    _Float16* VWh = (_Float16*)d_ws;
    _Float16* RWh = VWh + (size_t)NUM_V * HH;
    float* peProd = (float*)(RWh + (size_t)NUM_R * HH);
    unsigned short* wfrag = (unsigned short*)(peProd + HH);

    prep_kernel<<<81, 256, 0, stream>>>(R, WR, bR, RWh, WV, wfrag, P, WP, bP, peProd);
    const int tiles = (NUM_V + 31) / 32;              // 3125 (exact: 3125*32 = 100000)
    gemm_bres<<<(tiles + 11) / 12, 768, 0, stream>>>(V, wfrag, bV, VWh, NUM_V);
    gather_kernel<<<BB, 256, 0, stream>>>(r, e, VWh, RWh, peProd, out);
}

// Round 5
// 74.050 us; speedup vs baseline: 1.3739x; 1.1186x over previous
//
#include <hip/hip_runtime.h>

#define NUM_V 100000
#define NUM_R 1000
#define ARITY 3
#define DD 128
#define DI 192   /* D + I */
#define HH 128
#define BB 4096
#define NN 64

typedef __attribute__((ext_vector_type(8))) short short8;
typedef __attribute__((ext_vector_type(4))) float f32x4;
typedef __attribute__((ext_vector_type(4))) unsigned int u32x4;
typedef __attribute__((ext_vector_type(8))) _Float16 half8;
typedef __attribute__((ext_vector_type(2))) _Float16 half2v;

__device__ inline unsigned short f2bf(float f) {
    unsigned int u = __float_as_uint(f);
    unsigned int r = (u + 0x7fffu + ((u >> 16) & 1u)) >> 16;
    return (unsigned short)r;
}
__device__ inline float bf2f(unsigned short s) {
    return __uint_as_float(((unsigned int)s) << 16);
}

// split pair (f0,f1) -> {hi: packed truncated bf16 pair, lo: packed RNE bf16 of residual}
__device__ inline uint2 splitpair(float f0, float f1) {
    unsigned int u0 = __float_as_uint(f0), u1 = __float_as_uint(f1);
    unsigned int hp = __builtin_amdgcn_perm(u1, u0, 0x07060302u);  // {u0.hi16, u1.hi16}
    float r0 = f0 - __uint_as_float(u0 & 0xffff0000u);
    float r1 = f1 - __uint_as_float(u1 & 0xffff0000u);
    unsigned int lp = (unsigned int)f2bf(r0) | ((unsigned int)f2bf(r1) << 16);
    return make_uint2(hp, lp);
}

// async global->LDS, 16B per lane; LDS dest is wave-uniform base + lane*16
__device__ inline void gload16(const void* g, void* lds) {
    __builtin_amdgcn_global_load_lds(
        (const __attribute__((address_space(1))) unsigned int*)g,
        (__attribute__((address_space(3))) unsigned int*)lds, 16, 0, 0);
}

// ---------------- Fused prep: proj(R) | wfrag(WV) | pe --------------------
// blocks 0..31  : proj body (RWh = R @ WR + bR -> fp16)
// blocks 32..79 : wfrag body (split-bf16 W fragments, MFMA layout)
// block  80     : peProd[h] = prod_a (P[a]@WP + bP)[h]
__global__ __launch_bounds__(256) void prep_kernel(
    const float* __restrict__ R, const float* __restrict__ WR, const float* __restrict__ bR,
    _Float16* __restrict__ RWh,
    const float* __restrict__ WV, unsigned short* __restrict__ wf,
    const float* __restrict__ P, const float* __restrict__ WP, const float* __restrict__ bP,
    float* __restrict__ peProd) {
    const int bid = blockIdx.x;
    const int tid = threadIdx.x;

    if (bid < 32) {
        const int lane = tid & 63;
        const int wave = tid >> 6;
        const int wavesPerGrid = 32 * 4;
        const int waveId = bid * 4 + wave;
        const float2 b2 = ((const float2*)bR)[lane];
        const float2* __restrict__ W2 = (const float2*)WR;
        for (int rowBase0 = waveId * 8; rowBase0 < NUM_R; rowBase0 += wavesPerGrid * 8) {
            const int rowBase = __builtin_amdgcn_readfirstlane(rowBase0);
            float2 acc[8];
#pragma unroll
            for (int r8 = 0; r8 < 8; ++r8) acc[r8] = make_float2(0.f, 0.f);
#pragma unroll 4
            for (int k4 = 0; k4 < DD / 4; ++k4) {
                float4 v[8];
#pragma unroll
                for (int r8 = 0; r8 < 8; ++r8)
                    v[r8] = ((const float4*)(R + (size_t)(rowBase + r8) * DD))[k4];
#pragma unroll
                for (int kk = 0; kk < 4; ++kk) {
                    float2 w = W2[(k4 * 4 + kk) * 64 + lane];
#pragma unroll
                    for (int r8 = 0; r8 < 8; ++r8) {
                        float vv = (kk == 0) ? v[r8].x : (kk == 1) ? v[r8].y : (kk == 2) ? v[r8].z : v[r8].w;
                        acc[r8].x += vv * w.x;
                        acc[r8].y += vv * w.y;
                    }
                }
            }
#pragma unroll
            for (int r8 = 0; r8 < 8; ++r8) {
                if (rowBase + r8 < NUM_R) {
                    half2v h;
                    h.x = (_Float16)(acc[r8].x + b2.x);
                    h.y = (_Float16)(acc[r8].y + b2.y);
                    *(half2v*)(RWh + (size_t)(rowBase + r8) * HH + lane * 2) = h;
                }
            }
        }
    } else if (bid < 80) {
        if (tid < 64) {
            const int wb = bid - 32;
            const int ks = wb >> 3;  // 0..5
            const int ct = wb & 7;   // 0..7
            const int l = tid;       // 0..63
            const int col = ct * 16 + (l & 15);
            const int k0 = ks * 32 + (l >> 4) * 8;
            unsigned short hi[8], lo[8];
#pragma unroll
            for (int j = 0; j < 8; ++j) {
                float v = WV[(size_t)(k0 + j) * HH + col];
                unsigned short h = f2bf(v);
                hi[j] = h;
                lo[j] = f2bf(v - bf2f(h));
            }
            size_t base = (size_t)(ks * 8 + ct) * 2 * 512;
#pragma unroll
            for (int j = 0; j < 8; ++j) wf[base + l * 8 + j] = hi[j];
#pragma unroll
            for (int j = 0; j < 8; ++j) wf[base + 512 + l * 8 + j] = lo[j];
        }
    } else {
        if (tid < HH) {
            int h = tid;
            float prod = 1.0f;
            for (int a = 0; a < ARITY; ++a) {
                float acc = bP[h];
                for (int d = 0; d < DD; ++d) acc += P[a * DD + d] * WP[d * HH + h];
                prod *= acc;
            }
            peProd[h] = prod;
        }
    }
}

// ---------------- B-resident MFMA GEMM, tail-free launch geometry ------------
// C(fp16) = A @ W + bias. The ENTIRE split-bf16 W-fragment table (96 KB) is
// staged into LDS once per block; the main loop has ZERO barriers and ZERO
// global B-traffic. 1024 threads = 16 waves (4/SIMD), each wave owns exactly
// ONE 32x128 output tile; grid = ceil(3125/16) = 196 blocks < 256 CUs, so no
// CU ever runs a second block (round-4 tail: 5 CUs ran 2 blocks serially ->
// half the kernel at 0.7% occupancy). A is register-prefetched 2-deep; all
// waits are compiler-counted lgkm/vmcnt on straight-line code.
__global__ __launch_bounds__(1024, 4) void gemm_bres(const float* __restrict__ A,
                                                     const unsigned short* __restrict__ wf,
                                                     const float* __restrict__ bias,
                                                     _Float16* __restrict__ C, int M) {
    __shared__ unsigned short bsm[49152];  // 96 KB, byte-identical to wfrag layout

    const int tid = threadIdx.x;
    const int l = tid & 63;
    const int wv = tid >> 6;  // 0..15

    // ---- stage full wfrag: 16 waves x 6 x (64 lanes x 16B) = 96 KB, linear
#pragma unroll
    for (int i = 0; i < 6; ++i) {
        const int off = i * 16384 + wv * 1024;  // bytes, wave-uniform dest
        gload16((const char*)wf + off + l * 16, (char*)bsm + off);
    }

    const int tile = blockIdx.x * 16 + wv;  // 32-row tile id, one per wave
    const int rowbase = tile * 32;
    const bool active = rowbase < M;  // wave-uniform

    // bias per col-tile
    float bcol[8];
#pragma unroll
    for (int ct = 0; ct < 8; ++ct) bcol[ct] = bias[ct * 16 + (l & 15)];

    // A fragment pointers: row = rowbase + rt*16 + (l&15), k-base (l>>4)*8
    const float* aptr[2];
#pragma unroll
    for (int rt = 0; rt < 2; ++rt) {
        int rr = rowbase + rt * 16 + (l & 15);
        if (rr >= M) rr = M - 1;
        aptr[rt] = A + (size_t)rr * DI + (l >> 4) * 8;
    }

    f32x4 acc[2][8];
#pragma unroll
    for (int rt = 0; rt < 2; ++rt)
#pragma unroll
        for (int ct = 0; ct < 8; ++ct) acc[rt][ct] = (f32x4){0.f, 0.f, 0.f, 0.f};

    float4 va[2][2][2];  // [buf][rt][half]
#define LOAD_A(buf, ks)                                               \
    _Pragma("unroll") for (int rt = 0; rt < 2; ++rt) {                \
        va[buf][rt][0] = *(const float4*)(aptr[rt] + (ks) * 32);      \
        va[buf][rt][1] = *(const float4*)(aptr[rt] + (ks) * 32 + 4);  \
    }

    if (active) { LOAD_A(0, 0) }

    __syncthreads();  // the ONLY barrier: publishes LDS B-table to all waves
    if (!active) return;

#pragma unroll
    for (int ks = 0; ks < 6; ++ks) {
        const int cur = ks & 1;
        if (ks < 5) { LOAD_A(cur ^ 1, ks + 1) }

        // split-bf16 convert of the current A fragments
        short8 ah[2], al[2];
#pragma unroll
        for (int rt = 0; rt < 2; ++rt) {
            uint2 s0 = splitpair(va[cur][rt][0].x, va[cur][rt][0].y);
            uint2 s1 = splitpair(va[cur][rt][0].z, va[cur][rt][0].w);
            uint2 s2 = splitpair(va[cur][rt][1].x, va[cur][rt][1].y);
            uint2 s3 = splitpair(va[cur][rt][1].z, va[cur][rt][1].w);
            u32x4 hp = {s0.x, s1.x, s2.x, s3.x};
            u32x4 lp = {s0.y, s1.y, s2.y, s3.y};
            ah[rt] = __builtin_bit_cast(short8, hp);
            al[rt] = __builtin_bit_cast(short8, lp);
        }

#pragma unroll
        for (int ct = 0; ct < 8; ++ct) {
            const int fb = (ks * 8 + ct) * 1024;  // ushort index of fragment
            short8 bh = *(const short8*)&bsm[fb + l * 8];
            short8 bl = *(const short8*)&bsm[fb + 512 + l * 8];
#pragma unroll
            for (int rt = 0; rt < 2; ++rt) {
                acc[rt][ct] = __builtin_amdgcn_mfma_f32_16x16x32_bf16(ah[rt], bh, acc[rt][ct], 0, 0, 0);
                acc[rt][ct] = __builtin_amdgcn_mfma_f32_16x16x32_bf16(ah[rt], bl, acc[rt][ct], 0, 0, 0);
                acc[rt][ct] = __builtin_amdgcn_mfma_f32_16x16x32_bf16(al[rt], bh, acc[rt][ct], 0, 0, 0);
            }
        }
    }
#undef LOAD_A

    // epilogue: one wave writes full 256B C-lines (col=ct*16+(l&15))
#pragma unroll
    for (int rt = 0; rt < 2; ++rt) {
        const int rb = rowbase + rt * 16 + (l >> 4) * 4;
#pragma unroll
        for (int j = 0; j < 4; ++j) {
            const int row = rb + j;
            if (row < M) {
#pragma unroll
                for (int ct = 0; ct < 8; ++ct)
                    C[(size_t)row * HH + ct * 16 + (l & 15)] = (_Float16)(acc[rt][ct][j] + bcol[ct]);
            }
        }
    }
}

// ---------------- Gather - product - neighbor-sum (fp16 tables) --------------
// out[b,h] = peProd[h] * sum_n RWh[r[b,n]][h] * prod_a VWh[e[a,b,n]][h]
__global__ __launch_bounds__(256) void gather_kernel(const int* __restrict__ r,
                                                     const int* __restrict__ e,
                                                     const _Float16* __restrict__ VWh,
                                                     const _Float16* __restrict__ RWh,
                                                     const float* __restrict__ peProd,
                                                     float* __restrict__ out) {
    __shared__ int rIdx[NN];
    __shared__ int eIdx[ARITY][NN];
    __shared__ float4 partial[3][16][2];

    const int b = blockIdx.x;
    const int tid = threadIdx.x;

    if (tid < NN) {
        rIdx[tid] = r[b * NN + tid];
    } else {
        int t = tid - NN;
        eIdx[t >> 6][t & 63] = e[(size_t)(t >> 6) * BB * NN + b * NN + (t & 63)];
    }
    __syncthreads();

    const int lane = tid & 63;
    const int wv = tid >> 6;    // 0..3
    const int q = lane >> 4;    // neighbor sub-slot 0..3
    const int ho = lane & 15;   // h-octet: h = ho*8 .. +8

    float acc8[8];
#pragma unroll
    for (int k = 0; k < 8; ++k) acc8[k] = 0.f;

#pragma unroll
    for (int it = 0; it < 4; ++it) {
        int n = it * 16 + wv * 4 + q;
        half8 rw = *(const half8*)(RWh + (size_t)rIdx[n] * HH + ho * 8);
        half8 v0 = *(const half8*)(VWh + (size_t)eIdx[0][n] * HH + ho * 8);
        half8 v1 = *(const half8*)(VWh + (size_t)eIdx[1][n] * HH + ho * 8);
        half8 v2 = *(const half8*)(VWh + (size_t)eIdx[2][n] * HH + ho * 8);
        half8 p = rw * v0;
        p = p * v1;
        p = p * v2;
#pragma unroll
        for (int k = 0; k < 8; ++k) acc8[k] += (float)p[k];
    }

    // combine the 4 neighbor sub-slots (lane quarters share ho)
#pragma unroll
    for (int k = 0; k < 8; ++k) {
        acc8[k] += __shfl_xor(acc8[k], 16);
        acc8[k] += __shfl_xor(acc8[k], 32);
    }

    if (wv > 0 && lane < 16) {
        partial[wv - 1][ho][0] = make_float4(acc8[0], acc8[1], acc8[2], acc8[3]);
        partial[wv - 1][ho][1] = make_float4(acc8[4], acc8[5], acc8[6], acc8[7]);
    }
    __syncthreads();
    if (wv == 0 && lane < 16) {
        float4 s0 = make_float4(acc8[0], acc8[1], acc8[2], acc8[3]);
        float4 s1 = make_float4(acc8[4], acc8[5], acc8[6], acc8[7]);
#pragma unroll
        for (int g = 0; g < 3; ++g) {
            float4 t0 = partial[g][ho][0], t1 = partial[g][ho][1];
            s0.x += t0.x; s0.y += t0.y; s0.z += t0.z; s0.w += t0.w;
            s1.x += t1.x; s1.y += t1.y; s1.z += t1.z; s1.w += t1.w;
        }
        float4 p0 = ((const float4*)peProd)[ho * 2];
        float4 p1 = ((const float4*)peProd)[ho * 2 + 1];
        ((float4*)(out + (size_t)b * HH))[ho * 2] =
            make_float4(s0.x * p0.x, s0.y * p0.y, s0.z * p0.z, s0.w * p0.w);
        ((float4*)(out + (size_t)b * HH))[ho * 2 + 1] =
            make_float4(s1.x * p1.x, s1.y * p1.y, s1.z * p1.z, s1.w * p1.w);
    }
}

// ---------------- Launch -----------------------------------------------------
extern "C" void kernel_launch(void* const* d_in, const int* in_sizes, int n_in,
                              void* d_out, int out_size, void* d_ws, size_t ws_size,
                              hipStream_t stream) {
    const int* r = (const int*)d_in[0];
    const int* e = (const int*)d_in[1];
    const float* V = (const float*)d_in[2];
    const float* R = (const float*)d_in[3];
    const float* P = (const float*)d_in[4];
    const float* WV = (const float*)d_in[5];
    const float* bV = (const float*)d_in[6];
    const float* WR = (const float*)d_in[7];
    const float* bR = (const float*)d_in[8];
    const float* WP = (const float*)d_in[9];
    const float* bP = (const float*)d_in[10];
    float* out = (float*)d_out;

    // ws layout: VWh [NUM_V,H] fp16 | RWh [NUM_R,H] fp16 | peProd [H] f32 | Wfrag 96 KB
    _Float16* VWh = (_Float16*)d_ws;
    _Float16* RWh = VWh + (size_t)NUM_V * HH;
    float* peProd = (float*)(RWh + (size_t)NUM_R * HH);
    unsigned short* wfrag = (unsigned short*)(peProd + HH);

    prep_kernel<<<81, 256, 0, stream>>>(R, WR, bR, RWh, WV, wfrag, P, WP, bP, peProd);
    const int tiles = (NUM_V + 31) / 32;               // 3125 (exact: 3125*32 = 100000)
    gemm_bres<<<(tiles + 15) / 16, 1024, 0, stream>>>(V, wfrag, bV, VWh, NUM_V);
    gather_kernel<<<BB, 256, 0, stream>>>(r, e, VWh, RWh, peProd, out);
}

// Round 6
// 73.938 us; speedup vs baseline: 1.3760x; 1.0015x over previous
//
#include <hip/hip_runtime.h>

#define NUM_V 100000
#define NUM_R 1000
#define ARITY 3
#define DD 128
#define DI 192   /* D + I */
#define HH 128
#define BB 4096
#define NN 64

typedef __attribute__((ext_vector_type(8))) short short8;
typedef __attribute__((ext_vector_type(4))) float f32x4;
typedef __attribute__((ext_vector_type(4))) unsigned int u32x4;
typedef __attribute__((ext_vector_type(8))) _Float16 half8;
typedef __attribute__((ext_vector_type(2))) _Float16 half2v;

__device__ inline unsigned short f2bf(float f) {
    unsigned int u = __float_as_uint(f);
    unsigned int r = (u + 0x7fffu + ((u >> 16) & 1u)) >> 16;
    return (unsigned short)r;
}
__device__ inline float bf2f(unsigned short s) {
    return __uint_as_float(((unsigned int)s) << 16);
}

// split pair (f0,f1) -> {hi: packed truncated bf16 pair, lo: packed RNE bf16 of residual}
__device__ inline uint2 splitpair(float f0, float f1) {
    unsigned int u0 = __float_as_uint(f0), u1 = __float_as_uint(f1);
    unsigned int hp = __builtin_amdgcn_perm(u1, u0, 0x07060302u);  // {u0.hi16, u1.hi16}
    float r0 = f0 - __uint_as_float(u0 & 0xffff0000u);
    float r1 = f1 - __uint_as_float(u1 & 0xffff0000u);
    unsigned int lp = (unsigned int)f2bf(r0) | ((unsigned int)f2bf(r1) << 16);
    return make_uint2(hp, lp);
}

// async global->LDS, 16B per lane; LDS dest is wave-uniform base + lane*16
__device__ inline void gload16(const void* g, void* lds) {
    __builtin_amdgcn_global_load_lds(
        (const __attribute__((address_space(1))) unsigned int*)g,
        (__attribute__((address_space(3))) unsigned int*)lds, 16, 0, 0);
}

// ---------------- Fused prep: proj(R) | wfrag(WV) | pe --------------------
// blocks 0..31  : proj body (RWh = R @ WR + bR -> fp16)
// blocks 32..79 : wfrag body (split-bf16 W fragments, MFMA layout)
// block  80     : peProd[h] = prod_a (P[a]@WP + bP)[h]
__global__ __launch_bounds__(256) void prep_kernel(
    const float* __restrict__ R, const float* __restrict__ WR, const float* __restrict__ bR,
    _Float16* __restrict__ RWh,
    const float* __restrict__ WV, unsigned short* __restrict__ wf,
    const float* __restrict__ P, const float* __restrict__ WP, const float* __restrict__ bP,
    float* __restrict__ peProd) {
    const int bid = blockIdx.x;
    const int tid = threadIdx.x;

    if (bid < 32) {
        const int lane = tid & 63;
        const int wave = tid >> 6;
        const int wavesPerGrid = 32 * 4;
        const int waveId = bid * 4 + wave;
        const float2 b2 = ((const float2*)bR)[lane];
        const float2* __restrict__ W2 = (const float2*)WR;
        for (int rowBase0 = waveId * 8; rowBase0 < NUM_R; rowBase0 += wavesPerGrid * 8) {
            const int rowBase = __builtin_amdgcn_readfirstlane(rowBase0);
            float2 acc[8];
#pragma unroll
            for (int r8 = 0; r8 < 8; ++r8) acc[r8] = make_float2(0.f, 0.f);
#pragma unroll 4
            for (int k4 = 0; k4 < DD / 4; ++k4) {
                float4 v[8];
#pragma unroll
                for (int r8 = 0; r8 < 8; ++r8)
                    v[r8] = ((const float4*)(R + (size_t)(rowBase + r8) * DD))[k4];
#pragma unroll
                for (int kk = 0; kk < 4; ++kk) {
                    float2 w = W2[(k4 * 4 + kk) * 64 + lane];
#pragma unroll
                    for (int r8 = 0; r8 < 8; ++r8) {
                        float vv = (kk == 0) ? v[r8].x : (kk == 1) ? v[r8].y : (kk == 2) ? v[r8].z : v[r8].w;
                        acc[r8].x += vv * w.x;
                        acc[r8].y += vv * w.y;
                    }
                }
            }
#pragma unroll
            for (int r8 = 0; r8 < 8; ++r8) {
                if (rowBase + r8 < NUM_R) {
                    half2v h;
                    h.x = (_Float16)(acc[r8].x + b2.x);
                    h.y = (_Float16)(acc[r8].y + b2.y);
                    *(half2v*)(RWh + (size_t)(rowBase + r8) * HH + lane * 2) = h;
                }
            }
        }
    } else if (bid < 80) {
        if (tid < 64) {
            const int wb = bid - 32;
            const int ks = wb >> 3;  // 0..5
            const int ct = wb & 7;   // 0..7
            const int l = tid;       // 0..63
            const int col = ct * 16 + (l & 15);
            const int k0 = ks * 32 + (l >> 4) * 8;
            unsigned short hi[8], lo[8];
#pragma unroll
            for (int j = 0; j < 8; ++j) {
                float v = WV[(size_t)(k0 + j) * HH + col];
                unsigned short h = f2bf(v);
                hi[j] = h;
                lo[j] = f2bf(v - bf2f(h));
            }
            size_t base = (size_t)(ks * 8 + ct) * 2 * 512;
#pragma unroll
            for (int j = 0; j < 8; ++j) wf[base + l * 8 + j] = hi[j];
#pragma unroll
            for (int j = 0; j < 8; ++j) wf[base + 512 + l * 8 + j] = lo[j];
        }
    } else {
        if (tid < HH) {
            int h = tid;
            float prod = 1.0f;
            for (int a = 0; a < ARITY; ++a) {
                float acc = bP[h];
                for (int d = 0; d < DD; ++d) acc += P[a * DD + d] * WP[d * HH + h];
                prod *= acc;
            }
            peProd[h] = prod;
        }
    }
}

// ---------------- B-resident MFMA GEMM, all-CU interleaved geometry ----------
// C(fp16) = A @ W + bias. 96 KB split-bf16 W table staged to LDS once per
// block; main loop barrier-free, zero global B-traffic. 832 threads = 13
// waves; wave w of block b owns tile (w*256 + b): grid = 256 blocks puts work
// on EVERY CU (round 5 used only 196) with zero serial rounds. A is register-
// prefetched 3-deep (two steps of slack to cover loaded L3/HBM latency); all
// waits are compiler-counted lgkm/vmcnt on straight-line code.
__global__ __launch_bounds__(832, 3) void gemm_bres(const float* __restrict__ A,
                                                    const unsigned short* __restrict__ wf,
                                                    const float* __restrict__ bias,
                                                    _Float16* __restrict__ C, int M) {
    __shared__ unsigned short bsm[49152];  // 96 KB, byte-identical to wfrag layout

    const int tid = threadIdx.x;
    const int l = tid & 63;
    const int wv = tid >> 6;  // 0..12

    const int tile = wv * 256 + blockIdx.x;  // interleaved: all 256 CUs busy
    const int rowbase = tile * 32;
    const bool active = rowbase < M;  // wave-uniform (M = 3125*32 exactly)

    // bias per col-tile
    float bcol[8];
#pragma unroll
    for (int ct = 0; ct < 8; ++ct) bcol[ct] = bias[ct * 16 + (l & 15)];

    // A fragment pointers: row = rowbase + rt*16 + (l&15), k-base (l>>4)*8
    const float* aptr[2];
#pragma unroll
    for (int rt = 0; rt < 2; ++rt) {
        int rr = rowbase + rt * 16 + (l & 15);
        if (rr >= M) rr = M - 1;
        aptr[rt] = A + (size_t)rr * DI + (l >> 4) * 8;
    }

    f32x4 acc[2][8];
#pragma unroll
    for (int rt = 0; rt < 2; ++rt)
#pragma unroll
        for (int ct = 0; ct < 8; ++ct) acc[rt][ct] = (f32x4){0.f, 0.f, 0.f, 0.f};

    float4 va[3][2][2];  // [buf][rt][half] -- 3-deep pipeline, static indices
#define LOAD_A(buf, ks)                                               \
    _Pragma("unroll") for (int rt = 0; rt < 2; ++rt) {                \
        va[buf][rt][0] = *(const float4*)(aptr[rt] + (ks) * 32);      \
        va[buf][rt][1] = *(const float4*)(aptr[rt] + (ks) * 32 + 4);  \
    }

    // prologue A loads first (start HBM/L3 traffic earliest)
    if (active) {
        LOAD_A(0, 0)
        LOAD_A(1, 1)
    }

    // ---- stage full wfrag: waves 0..11 stage 8 KB each = 96 KB, linear
    if (wv < 12) {
#pragma unroll
        for (int i = 0; i < 8; ++i) {
            const int off = wv * 8192 + i * 1024;  // bytes, wave-uniform dest
            gload16((const char*)wf + off + l * 16, (char*)bsm + off);
        }
    }

    __syncthreads();  // the ONLY barrier: publishes LDS B-table to all waves
    if (!active) return;

#pragma unroll
    for (int ks = 0; ks < 6; ++ks) {
        const int cur = ks % 3;
        if (ks < 4) { LOAD_A((ks + 2) % 3, ks + 2) }

        // split-bf16 convert of the current A fragments
        short8 ah[2], al[2];
#pragma unroll
        for (int rt = 0; rt < 2; ++rt) {
            uint2 s0 = splitpair(va[cur][rt][0].x, va[cur][rt][0].y);
            uint2 s1 = splitpair(va[cur][rt][0].z, va[cur][rt][0].w);
            uint2 s2 = splitpair(va[cur][rt][1].x, va[cur][rt][1].y);
            uint2 s3 = splitpair(va[cur][rt][1].z, va[cur][rt][1].w);
            u32x4 hp = {s0.x, s1.x, s2.x, s3.x};
            u32x4 lp = {s0.y, s1.y, s2.y, s3.y};
            ah[rt] = __builtin_bit_cast(short8, hp);
            al[rt] = __builtin_bit_cast(short8, lp);
        }

#pragma unroll
        for (int ct = 0; ct < 8; ++ct) {
            const int fb = (ks * 8 + ct) * 1024;  // ushort index of fragment
            short8 bh = *(const short8*)&bsm[fb + l * 8];
            short8 bl = *(const short8*)&bsm[fb + 512 + l * 8];
#pragma unroll
            for (int rt = 0; rt < 2; ++rt) {
                acc[rt][ct] = __builtin_amdgcn_mfma_f32_16x16x32_bf16(ah[rt], bh, acc[rt][ct], 0, 0, 0);
                acc[rt][ct] = __builtin_amdgcn_mfma_f32_16x16x32_bf16(ah[rt], bl, acc[rt][ct], 0, 0, 0);
                acc[rt][ct] = __builtin_amdgcn_mfma_f32_16x16x32_bf16(al[rt], bh, acc[rt][ct], 0, 0, 0);
            }
        }
    }
#undef LOAD_A

    // epilogue: one wave writes full 256B C-lines (col=ct*16+(l&15))
#pragma unroll
    for (int rt = 0; rt < 2; ++rt) {
        const int rb = rowbase + rt * 16 + (l >> 4) * 4;
#pragma unroll
        for (int j = 0; j < 4; ++j) {
            const int row = rb + j;
            if (row < M) {
#pragma unroll
                for (int ct = 0; ct < 8; ++ct)
                    C[(size_t)row * HH + ct * 16 + (l & 15)] = (_Float16)(acc[rt][ct][j] + bcol[ct]);
            }
        }
    }
}

// ---------------- Gather - product - neighbor-sum (fp16 tables) --------------
// out[b,h] = peProd[h] * sum_n RWh[r[b,n]][h] * prod_a VWh[e[a,b,n]][h]
__global__ __launch_bounds__(256) void gather_kernel(const int* __restrict__ r,
                                                     const int* __restrict__ e,
                                                     const _Float16* __restrict__ VWh,
                                                     const _Float16* __restrict__ RWh,
                                                     const float* __restrict__ peProd,
                                                     float* __restrict__ out) {
    __shared__ int rIdx[NN];
    __shared__ int eIdx[ARITY][NN];
    __shared__ float4 partial[3][16][2];

    const int b = blockIdx.x;
    const int tid = threadIdx.x;

    if (tid < NN) {
        rIdx[tid] = r[b * NN + tid];
    } else {
        int t = tid - NN;
        eIdx[t >> 6][t & 63] = e[(size_t)(t >> 6) * BB * NN + b * NN + (t & 63)];
    }
    __syncthreads();

    const int lane = tid & 63;
    const int wv = tid >> 6;    // 0..3
    const int q = lane >> 4;    // neighbor sub-slot 0..3
    const int ho = lane & 15;   // h-octet: h = ho*8 .. +8

    float acc8[8];
#pragma unroll
    for (int k = 0; k < 8; ++k) acc8[k] = 0.f;

#pragma unroll
    for (int it = 0; it < 4; ++it) {
        int n = it * 16 + wv * 4 + q;
        half8 rw = *(const half8*)(RWh + (size_t)rIdx[n] * HH + ho * 8);
        half8 v0 = *(const half8*)(VWh + (size_t)eIdx[0][n] * HH + ho * 8);
        half8 v1 = *(const half8*)(VWh + (size_t)eIdx[1][n] * HH + ho * 8);
        half8 v2 = *(const half8*)(VWh + (size_t)eIdx[2][n] * HH + ho * 8);
        half8 p = rw * v0;
        p = p * v1;
        p = p * v2;
#pragma unroll
        for (int k = 0; k < 8; ++k) acc8[k] += (float)p[k];
    }

    // combine the 4 neighbor sub-slots (lane quarters share ho)
#pragma unroll
    for (int k = 0; k < 8; ++k) {
        acc8[k] += __shfl_xor(acc8[k], 16);
        acc8[k] += __shfl_xor(acc8[k], 32);
    }

    if (wv > 0 && lane < 16) {
        partial[wv - 1][ho][0] = make_float4(acc8[0], acc8[1], acc8[2], acc8[3]);
        partial[wv - 1][ho][1] = make_float4(acc8[4], acc8[5], acc8[6], acc8[7]);
    }
    __syncthreads();
    if (wv == 0 && lane < 16) {
        float4 s0 = make_float4(acc8[0], acc8[1], acc8[2], acc8[3]);
        float4 s1 = make_float4(acc8[4], acc8[5], acc8[6], acc8[7]);
#pragma unroll
        for (int g = 0; g < 3; ++g) {
            float4 t0 = partial[g][ho][0], t1 = partial[g][ho][1];
            s0.x += t0.x; s0.y += t0.y; s0.z += t0.z; s0.w += t0.w;
            s1.x += t1.x; s1.y += t1.y; s1.z += t1.z; s1.w += t1.w;
        }
        float4 p0 = ((const float4*)peProd)[ho * 2];
        float4 p1 = ((const float4*)peProd)[ho * 2 + 1];
        ((float4*)(out + (size_t)b * HH))[ho * 2] =
            make_float4(s0.x * p0.x, s0.y * p0.y, s0.z * p0.z, s0.w * p0.w);
        ((float4*)(out + (size_t)b * HH))[ho * 2 + 1] =
            make_float4(s1.x * p1.x, s1.y * p1.y, s1.z * p1.z, s1.w * p1.w);
    }
}

// ---------------- Launch -----------------------------------------------------
extern "C" void kernel_launch(void* const* d_in, const int* in_sizes, int n_in,
                              void* d_out, int out_size, void* d_ws, size_t ws_size,
                              hipStream_t stream) {
    const int* r = (const int*)d_in[0];
    const int* e = (const int*)d_in[1];
    const float* V = (const float*)d_in[2];
    const float* R = (const float*)d_in[3];
    const float* P = (const float*)d_in[4];
    const float* WV = (const float*)d_in[5];
    const float* bV = (const float*)d_in[6];
    const float* WR = (const float*)d_in[7];
    const float* bR = (const float*)d_in[8];
    const float* WP = (const float*)d_in[9];
    const float* bP = (const float*)d_in[10];
    float* out = (float*)d_out;

    // ws layout: VWh [NUM_V,H] fp16 | RWh [NUM_R,H] fp16 | peProd [H] f32 | Wfrag 96 KB
    _Float16* VWh = (_Float16*)d_ws;
    _Float16* RWh = VWh + (size_t)NUM_V * HH;
    float* peProd = (float*)(RWh + (size_t)NUM_R * HH);
    unsigned short* wfrag = (unsigned short*)(peProd + HH);

    prep_kernel<<<81, 256, 0, stream>>>(R, WR, bR, RWh, WV, wfrag, P, WP, bP, peProd);
    gemm_bres<<<256, 832, 0, stream>>>(V, wfrag, bV, VWh, NUM_V);
    gather_kernel<<<BB, 256, 0, stream>>>(r, e, VWh, RWh, peProd, out);
}

// Round 7
// 71.118 us; speedup vs baseline: 1.4306x; 1.0396x over previous
//
#include <hip/hip_runtime.h>

#define NUM_V 100000
#define NUM_R 1000
#define ARITY 3
#define DD 128
#define DI 192   /* D + I */
#define HH 128
#define BB 4096
#define NN 64

typedef __attribute__((ext_vector_type(4))) float f32x4;
typedef __attribute__((ext_vector_type(8))) _Float16 half8;
typedef __attribute__((ext_vector_type(2))) _Float16 half2v;

// async global->LDS, 16B per lane; LDS dest is wave-uniform base + lane*16
__device__ inline void gload16(const void* g, void* lds) {
    __builtin_amdgcn_global_load_lds(
        (const __attribute__((address_space(1))) unsigned int*)g,
        (__attribute__((address_space(3))) unsigned int*)lds, 16, 0, 0);
}

// ---------------- Fused prep: proj(R) | wfrag(WV, f16) | pe ------------------
// blocks 0..31  : proj body (RWh = R @ WR + bR -> fp16)
// blocks 32..79 : wfrag body (f16 W fragments, MFMA layout, single table)
// block  80     : peProd[h] = prod_a (P[a]@WP + bP)[h]
__global__ __launch_bounds__(256) void prep_kernel(
    const float* __restrict__ R, const float* __restrict__ WR, const float* __restrict__ bR,
    _Float16* __restrict__ RWh,
    const float* __restrict__ WV, unsigned short* __restrict__ wf,
    const float* __restrict__ P, const float* __restrict__ WP, const float* __restrict__ bP,
    float* __restrict__ peProd) {
    const int bid = blockIdx.x;
    const int tid = threadIdx.x;

    if (bid < 32) {
        const int lane = tid & 63;
        const int wave = tid >> 6;
        const int wavesPerGrid = 32 * 4;
        const int waveId = bid * 4 + wave;
        const float2 b2 = ((const float2*)bR)[lane];
        const float2* __restrict__ W2 = (const float2*)WR;
        for (int rowBase0 = waveId * 8; rowBase0 < NUM_R; rowBase0 += wavesPerGrid * 8) {
            const int rowBase = __builtin_amdgcn_readfirstlane(rowBase0);
            float2 acc[8];
#pragma unroll
            for (int r8 = 0; r8 < 8; ++r8) acc[r8] = make_float2(0.f, 0.f);
#pragma unroll 4
            for (int k4 = 0; k4 < DD / 4; ++k4) {
                float4 v[8];
#pragma unroll
                for (int r8 = 0; r8 < 8; ++r8)
                    v[r8] = ((const float4*)(R + (size_t)(rowBase + r8) * DD))[k4];
#pragma unroll
                for (int kk = 0; kk < 4; ++kk) {
                    float2 w = W2[(k4 * 4 + kk) * 64 + lane];
#pragma unroll
                    for (int r8 = 0; r8 < 8; ++r8) {
                        float vv = (kk == 0) ? v[r8].x : (kk == 1) ? v[r8].y : (kk == 2) ? v[r8].z : v[r8].w;
                        acc[r8].x += vv * w.x;
                        acc[r8].y += vv * w.y;
                    }
                }
            }
#pragma unroll
            for (int r8 = 0; r8 < 8; ++r8) {
                if (rowBase + r8 < NUM_R) {
                    half2v h;
                    h.x = (_Float16)(acc[r8].x + b2.x);
                    h.y = (_Float16)(acc[r8].y + b2.y);
                    *(half2v*)(RWh + (size_t)(rowBase + r8) * HH + lane * 2) = h;
                }
            }
        }
    } else if (bid < 80) {
        // ---- wfrag (f16): wf[kstep(6)][ctile(8)][lane(64)][j(8)] ushort(f16 bits)
        if (tid < 64) {
            const int wb = bid - 32;
            const int ks = wb >> 3;  // 0..5
            const int ct = wb & 7;   // 0..7
            const int l = tid;       // 0..63
            const int col = ct * 16 + (l & 15);
            const int k0 = ks * 32 + (l >> 4) * 8;
            size_t base = (size_t)(ks * 8 + ct) * 512;
#pragma unroll
            for (int j = 0; j < 8; ++j) {
                float v = WV[(size_t)(k0 + j) * HH + col];
                wf[base + l * 8 + j] = __builtin_bit_cast(unsigned short, (_Float16)v);
            }
        }
    } else {
        if (tid < HH) {
            int h = tid;
            float prod = 1.0f;
            for (int a = 0; a < ARITY; ++a) {
                float acc = bP[h];
                for (int d = 0; d < DD; ++d) acc += P[a * DD + d] * WP[d * HH + h];
                prod *= acc;
            }
            peProd[h] = prod;
        }
    }
}

// ---------------- B-resident f16 MFMA GEMM -----------------------------------
// C(fp16) = A @ W + bias, single-MFMA f16 path. Rationale: VWh is stored fp16
// (rel 2^-12) and gather multiplies in fp16 (rel ~2^-9), so split-bf16's
// 2^-16 A-precision was wasted. f16 inputs (2^-12 RNE) match the storage
// quantization. Per K-step: 16 v_cvt_f16_f32 + 8 ds_read_b128 + 16 MFMA
// (was ~120 VALU + 16 ds_read + 48 MFMA). W table 48 KB LDS, staged once.
// Geometry identical to round 6: 256 blocks x 13 waves, wave w owns tile
// w*256+bid (all CUs, zero serial rounds), 3-deep A register prefetch,
// barrier-free main loop.
__global__ __launch_bounds__(832, 4) void gemm_bres(const float* __restrict__ A,
                                                    const unsigned short* __restrict__ wf,
                                                    const float* __restrict__ bias,
                                                    _Float16* __restrict__ C, int M) {
    __shared__ unsigned short bsm[24576];  // 48 KB, byte-identical to wfrag layout

    const int tid = threadIdx.x;
    const int l = tid & 63;
    const int wv = tid >> 6;  // 0..12

    const int tile = wv * 256 + blockIdx.x;  // interleaved: all 256 CUs busy
    const int rowbase = tile * 32;
    const bool active = rowbase < M;  // wave-uniform (M = 3125*32 exactly)

    // bias per col-tile
    float bcol[8];
#pragma unroll
    for (int ct = 0; ct < 8; ++ct) bcol[ct] = bias[ct * 16 + (l & 15)];

    // A fragment pointers: row = rowbase + rt*16 + (l&15), k-base (l>>4)*8
    const float* aptr[2];
#pragma unroll
    for (int rt = 0; rt < 2; ++rt) {
        int rr = rowbase + rt * 16 + (l & 15);
        if (rr >= M) rr = M - 1;
        aptr[rt] = A + (size_t)rr * DI + (l >> 4) * 8;
    }

    f32x4 acc[2][8];
#pragma unroll
    for (int rt = 0; rt < 2; ++rt)
#pragma unroll
        for (int ct = 0; ct < 8; ++ct) acc[rt][ct] = (f32x4){0.f, 0.f, 0.f, 0.f};

    float4 va[3][2][2];  // [buf][rt][half] -- 3-deep pipeline, static indices
#define LOAD_A(buf, ks)                                               \
    _Pragma("unroll") for (int rt = 0; rt < 2; ++rt) {                \
        va[buf][rt][0] = *(const float4*)(aptr[rt] + (ks) * 32);      \
        va[buf][rt][1] = *(const float4*)(aptr[rt] + (ks) * 32 + 4);  \
    }

    // prologue A loads first (start HBM/L3 traffic earliest)
    if (active) {
        LOAD_A(0, 0)
        LOAD_A(1, 1)
    }

    // ---- stage f16 W table: waves 0..11 stage 4 KB each = 48 KB, linear
    if (wv < 12) {
#pragma unroll
        for (int i = 0; i < 4; ++i) {
            const int off = wv * 4096 + i * 1024;  // bytes, wave-uniform dest
            gload16((const char*)wf + off + l * 16, (char*)bsm + off);
        }
    }

    __syncthreads();  // the ONLY barrier: publishes LDS W-table to all waves
    if (!active) return;

#pragma unroll
    for (int ks = 0; ks < 6; ++ks) {
        const int cur = ks % 3;
        if (ks < 4) { LOAD_A((ks + 2) % 3, ks + 2) }

        // fp32 -> f16 convert of current A fragments (16 v_cvt, RNE)
        half8 ah[2];
#pragma unroll
        for (int rt = 0; rt < 2; ++rt) {
            half8 t;
            t[0] = (_Float16)va[cur][rt][0].x;
            t[1] = (_Float16)va[cur][rt][0].y;
            t[2] = (_Float16)va[cur][rt][0].z;
            t[3] = (_Float16)va[cur][rt][0].w;
            t[4] = (_Float16)va[cur][rt][1].x;
            t[5] = (_Float16)va[cur][rt][1].y;
            t[6] = (_Float16)va[cur][rt][1].z;
            t[7] = (_Float16)va[cur][rt][1].w;
            ah[rt] = t;
        }

#pragma unroll
        for (int ct = 0; ct < 8; ++ct) {
            const int fb = (ks * 8 + ct) * 512;  // ushort index of fragment
            half8 bh = *(const half8*)&bsm[fb + l * 8];
#pragma unroll
            for (int rt = 0; rt < 2; ++rt)
                acc[rt][ct] = __builtin_amdgcn_mfma_f32_16x16x32_f16(ah[rt], bh, acc[rt][ct], 0, 0, 0);
        }
    }
#undef LOAD_A

    // epilogue: one wave writes full 256B C-lines (col=ct*16+(l&15))
#pragma unroll
    for (int rt = 0; rt < 2; ++rt) {
        const int rb = rowbase + rt * 16 + (l >> 4) * 4;
#pragma unroll
        for (int j = 0; j < 4; ++j) {
            const int row = rb + j;
            if (row < M) {
#pragma unroll
                for (int ct = 0; ct < 8; ++ct)
                    C[(size_t)row * HH + ct * 16 + (l & 15)] = (_Float16)(acc[rt][ct][j] + bcol[ct]);
            }
        }
    }
}

// ---------------- Gather - product - neighbor-sum (fp16 tables) --------------
// out[b,h] = peProd[h] * sum_n RWh[r[b,n]][h] * prod_a VWh[e[a,b,n]][h]
__global__ __launch_bounds__(256) void gather_kernel(const int* __restrict__ r,
                                                     const int* __restrict__ e,
                                                     const _Float16* __restrict__ VWh,
                                                     const _Float16* __restrict__ RWh,
                                                     const float* __restrict__ peProd,
                                                     float* __restrict__ out) {
    __shared__ int rIdx[NN];
    __shared__ int eIdx[ARITY][NN];
    __shared__ float4 partial[3][16][2];

    const int b = blockIdx.x;
    const int tid = threadIdx.x;

    if (tid < NN) {
        rIdx[tid] = r[b * NN + tid];
    } else {
        int t = tid - NN;
        eIdx[t >> 6][t & 63] = e[(size_t)(t >> 6) * BB * NN + b * NN + (t & 63)];
    }
    __syncthreads();

    const int lane = tid & 63;
    const int wv = tid >> 6;    // 0..3
    const int q = lane >> 4;    // neighbor sub-slot 0..3
    const int ho = lane & 15;   // h-octet: h = ho*8 .. +8

    float acc8[8];
#pragma unroll
    for (int k = 0; k < 8; ++k) acc8[k] = 0.f;

#pragma unroll
    for (int it = 0; it < 4; ++it) {
        int n = it * 16 + wv * 4 + q;
        half8 rw = *(const half8*)(RWh + (size_t)rIdx[n] * HH + ho * 8);
        half8 v0 = *(const half8*)(VWh + (size_t)eIdx[0][n] * HH + ho * 8);
        half8 v1 = *(const half8*)(VWh + (size_t)eIdx[1][n] * HH + ho * 8);
        half8 v2 = *(const half8*)(VWh + (size_t)eIdx[2][n] * HH + ho * 8);
        half8 p = rw * v0;
        p = p * v1;
        p = p * v2;
#pragma unroll
        for (int k = 0; k < 8; ++k) acc8[k] += (float)p[k];
    }

    // combine the 4 neighbor sub-slots (lane quarters share ho)
#pragma unroll
    for (int k = 0; k < 8; ++k) {
        acc8[k] += __shfl_xor(acc8[k], 16);
        acc8[k] += __shfl_xor(acc8[k], 32);
    }

    if (wv > 0 && lane < 16) {
        partial[wv - 1][ho][0] = make_float4(acc8[0], acc8[1], acc8[2], acc8[3]);
        partial[wv - 1][ho][1] = make_float4(acc8[4], acc8[5], acc8[6], acc8[7]);
    }
    __syncthreads();
    if (wv == 0 && lane < 16) {
        float4 s0 = make_float4(acc8[0], acc8[1], acc8[2], acc8[3]);
        float4 s1 = make_float4(acc8[4], acc8[5], acc8[6], acc8[7]);
#pragma unroll
        for (int g = 0; g < 3; ++g) {
            float4 t0 = partial[g][ho][0], t1 = partial[g][ho][1];
            s0.x += t0.x; s0.y += t0.y; s0.z += t0.z; s0.w += t0.w;
            s1.x += t1.x; s1.y += t1.y; s1.z += t1.z; s1.w += t1.w;
        }
        float4 p0 = ((const float4*)peProd)[ho * 2];
        float4 p1 = ((const float4*)peProd)[ho * 2 + 1];
        ((float4*)(out + (size_t)b * HH))[ho * 2] =
            make_float4(s0.x * p0.x, s0.y * p0.y, s0.z * p0.z, s0.w * p0.w);
        ((float4*)(out + (size_t)b * HH))[ho * 2 + 1] =
            make_float4(s1.x * p1.x, s1.y * p1.y, s1.z * p1.z, s1.w * p1.w);
    }
}

// ---------------- Launch -----------------------------------------------------
extern "C" void kernel_launch(void* const* d_in, const int* in_sizes, int n_in,
                              void* d_out, int out_size, void* d_ws, size_t ws_size,
                              hipStream_t stream) {
    const int* r = (const int*)d_in[0];
    const int* e = (const int*)d_in[1];
    const float* V = (const float*)d_in[2];
    const float* R = (const float*)d_in[3];
    const float* P = (const float*)d_in[4];
    const float* WV = (const float*)d_in[5];
    const float* bV = (const float*)d_in[6];
    const float* WR = (const float*)d_in[7];
    const float* bR = (const float*)d_in[8];
    const float* WP = (const float*)d_in[9];
    const float* bP = (const float*)d_in[10];
    float* out = (float*)d_out;

    // ws layout: VWh [NUM_V,H] fp16 | RWh [NUM_R,H] fp16 | peProd [H] f32 | Wfrag 48 KB (f16)
    _Float16* VWh = (_Float16*)d_ws;
    _Float16* RWh = VWh + (size_t)NUM_V * HH;
    float* peProd = (float*)(RWh + (size_t)NUM_R * HH);
    unsigned short* wfrag = (unsigned short*)(peProd + HH);

    prep_kernel<<<81, 256, 0, stream>>>(R, WR, bR, RWh, WV, wfrag, P, WP, bP, peProd);
    gemm_bres<<<256, 832, 0, stream>>>(V, wfrag, bV, VWh, NUM_V);
    gather_kernel<<<BB, 256, 0, stream>>>(r, e, VWh, RWh, peProd, out);
}

// Round 8
// 70.457 us; speedup vs baseline: 1.4440x; 1.0094x over previous
//
#include <hip/hip_runtime.h>

#define NUM_V 100000
#define NUM_R 1000
#define ARITY 3
#define DD 128
#define DI 192   /* D + I */
#define HH 128
#define BB 4096
#define NN 64

typedef __attribute__((ext_vector_type(4))) float f32x4;
typedef __attribute__((ext_vector_type(8))) _Float16 half8;
typedef __attribute__((ext_vector_type(2))) _Float16 half2v;

// async global->LDS, 16B per lane; LDS dest is wave-uniform base, HW adds lane*16
__device__ inline void gload16(const void* g, void* lds) {
    __builtin_amdgcn_global_load_lds(
        (const __attribute__((address_space(1))) unsigned int*)g,
        (__attribute__((address_space(3))) unsigned int*)lds, 16, 0, 0);
}

// ---------------- Fused prep: proj(R) | wfrag(WV, f16) | pe ------------------
// blocks 0..31  : proj body (RWh = R @ WR + bR -> fp16)
// blocks 32..79 : wfrag body (f16 W fragments, MFMA layout, single table)
// block  80     : peProd[h] = prod_a (P[a]@WP + bP)[h]
__global__ __launch_bounds__(256) void prep_kernel(
    const float* __restrict__ R, const float* __restrict__ WR, const float* __restrict__ bR,
    _Float16* __restrict__ RWh,
    const float* __restrict__ WV, unsigned short* __restrict__ wf,
    const float* __restrict__ P, const float* __restrict__ WP, const float* __restrict__ bP,
    float* __restrict__ peProd) {
    const int bid = blockIdx.x;
    const int tid = threadIdx.x;

    if (bid < 32) {
        const int lane = tid & 63;
        const int wave = tid >> 6;
        const int wavesPerGrid = 32 * 4;
        const int waveId = bid * 4 + wave;
        const float2 b2 = ((const float2*)bR)[lane];
        const float2* __restrict__ W2 = (const float2*)WR;
        for (int rowBase0 = waveId * 8; rowBase0 < NUM_R; rowBase0 += wavesPerGrid * 8) {
            const int rowBase = __builtin_amdgcn_readfirstlane(rowBase0);
            float2 acc[8];
#pragma unroll
            for (int r8 = 0; r8 < 8; ++r8) acc[r8] = make_float2(0.f, 0.f);
#pragma unroll 4
            for (int k4 = 0; k4 < DD / 4; ++k4) {
                float4 v[8];
#pragma unroll
                for (int r8 = 0; r8 < 8; ++r8)
                    v[r8] = ((const float4*)(R + (size_t)(rowBase + r8) * DD))[k4];
#pragma unroll
                for (int kk = 0; kk < 4; ++kk) {
                    float2 w = W2[(k4 * 4 + kk) * 64 + lane];
#pragma unroll
                    for (int r8 = 0; r8 < 8; ++r8) {
                        float vv = (kk == 0) ? v[r8].x : (kk == 1) ? v[r8].y : (kk == 2) ? v[r8].z : v[r8].w;
                        acc[r8].x += vv * w.x;
                        acc[r8].y += vv * w.y;
                    }
                }
            }
#pragma unroll
            for (int r8 = 0; r8 < 8; ++r8) {
                if (rowBase + r8 < NUM_R) {
                    half2v h;
                    h.x = (_Float16)(acc[r8].x + b2.x);
                    h.y = (_Float16)(acc[r8].y + b2.y);
                    *(half2v*)(RWh + (size_t)(rowBase + r8) * HH + lane * 2) = h;
                }
            }
        }
    } else if (bid < 80) {
        // ---- wfrag (f16): wf[kstep(6)][ctile(8)][lane(64)][j(8)] ushort(f16 bits)
        if (tid < 64) {
            const int wb = bid - 32;
            const int ks = wb >> 3;  // 0..5
            const int ct = wb & 7;   // 0..7
            const int l = tid;       // 0..63
            const int col = ct * 16 + (l & 15);
            const int k0 = ks * 32 + (l >> 4) * 8;
            size_t base = (size_t)(ks * 8 + ct) * 512;
#pragma unroll
            for (int j = 0; j < 8; ++j) {
                float v = WV[(size_t)(k0 + j) * HH + col];
                wf[base + l * 8 + j] = __builtin_bit_cast(unsigned short, (_Float16)v);
            }
        }
    } else {
        if (tid < HH) {
            int h = tid;
            float prod = 1.0f;
            for (int a = 0; a < ARITY; ++a) {
                float acc = bP[h];
                for (int d = 0; d < DD; ++d) acc += P[a * DD + d] * WP[d * HH + h];
                prod *= acc;
            }
            peProd[h] = prod;
        }
    }
}

// ---------------- B-resident f16 GEMM, coalesced LDS-staged A ----------------
// C(fp16) = A @ W + bias. W table (48 KB f16) resident in LDS; A staged per
// K-step into WAVE-PRIVATE 4KB LDS slots via global_load_lds: each instr
// reads 8 rows x 128B DENSE (16 fully-used sectors, wave-uniform) vs the old
// scattered fragment loads (32 half-sectors/instr) that saturated the per-wave
// memory request queue at ~2KB in flight (measured 1.4-1.9 TB/s equilibrium).
// Wave-private slots -> NO barriers; per-wave counted vmcnt(4) on a 2-slot
// ring with +2-step lookahead. Slot-reuse race closed by lgkmcnt(0)+
// sched_barrier(0) between ds_reads and the overwriting stage. XOR chunk
// swizzle (source + read, involution) -> 2-way bank aliasing only.
__global__ __launch_bounds__(832) void gemm_bres(const float* __restrict__ A,
                                                 const unsigned short* __restrict__ wf,
                                                 const float* __restrict__ bias,
                                                 _Float16* __restrict__ C, int M) {
    __shared__ unsigned short bsm[24576];      // 48 KB B table
    __shared__ float aslots[13][2][1024];      // 13 waves x 2 slots x 4 KB = 104 KB

    const int tid = threadIdx.x;
    const int l = tid & 63;
    const int wv = tid >> 6;  // 0..12

    const int tile = wv * 256 + blockIdx.x;  // interleaved: all 256 CUs busy
    const int rowbase = tile * 32;
    const bool active = rowbase < M;  // wave-uniform (M = 3125*32 exactly)

    // bias per col-tile
    float bcol[8];
#pragma unroll
    for (int ct = 0; ct < 8; ++ct) bcol[ct] = bias[ct * 16 + (l & 15)];

    // ---- staging source: lane l covers local row (l>>3) (+8 per instr),
    // chunk position l&7; source chunk pre-swizzled (rule #21):
    // schunk = (l&7) ^ (row&7), row&7 == l>>3 for every instr (i*8 offset).
    const float* aSrc = A + (size_t)(rowbase + (l >> 3)) * DI + (((l & 7) ^ (l >> 3)) << 2);

    // ---- fragment ds_read float-offsets within a slot (chunk-swizzled):
    // lane reads row R = rt*16 + (l&15), chunks 2q, 2q+1 (q = l>>4)
    int aoff[2][2];
#pragma unroll
    for (int rt = 0; rt < 2; ++rt) {
        const int Rr = rt * 16 + (l & 15);
        const int q = l >> 4;
#pragma unroll
        for (int k = 0; k < 2; ++k)
            aoff[rt][k] = Rr * 32 + (((2 * q + k) ^ (Rr & 7)) << 2);
    }

    f32x4 acc[2][8];
#pragma unroll
    for (int rt = 0; rt < 2; ++rt)
#pragma unroll
        for (int ct = 0; ct < 8; ++ct) acc[rt][ct] = (f32x4){0.f, 0.f, 0.f, 0.f};

#define STAGE_A(slot, ks)                                                   \
    do {                                                                    \
        _Pragma("unroll") for (int i = 0; i < 4; ++i)                       \
            gload16(aSrc + (ks) * 32 + i * 8 * DI, &aslots[wv][slot][i * 256]); \
    } while (0)

#define WAITV(n) asm volatile("s_waitcnt vmcnt(" #n ")" ::: "memory")

    // prologue: A steps 0,1 (coalesced) + B table; syncthreads drains all
    if (active) {
        STAGE_A(0, 0);
        STAGE_A(1, 1);
    }
    if (wv < 12) {
#pragma unroll
        for (int i = 0; i < 4; ++i) {
            const int off = wv * 4096 + i * 1024;  // bytes, wave-uniform dest
            gload16((const char*)wf + off + l * 16, (char*)bsm + off);
        }
    }

    __syncthreads();  // the ONLY barrier: publishes B table (drains prologue)
    if (!active) return;

#pragma unroll
    for (int ks = 0; ks < 6; ++ks) {
        const int slot = ks & 1;

        // counted wait for A(ks): outstanding = {A(ks), A(ks+1)} => vmcnt(4)
        if (ks == 2 || ks == 3 || ks == 4) {
            WAITV(4);
            __builtin_amdgcn_sched_barrier(0);
        } else if (ks == 5) {
            WAITV(0);
            __builtin_amdgcn_sched_barrier(0);
        }

        // LDS -> regs: A fragments (4 x ds_read_b128, 2-way bank alias = free)
        f32x4 av[2][2];
#pragma unroll
        for (int rt = 0; rt < 2; ++rt) {
            av[rt][0] = *(const f32x4*)&aslots[wv][slot][aoff[rt][0]];
            av[rt][1] = *(const f32x4*)&aslots[wv][slot][aoff[rt][1]];
        }
        // B fragments (8 x ds_read_b128, conflict-free)
        half8 bh[8];
#pragma unroll
        for (int ct = 0; ct < 8; ++ct)
            bh[ct] = *(const half8*)&bsm[(ks * 8 + ct) * 512 + l * 8];

        // all LDS read DATA in registers before the slot is overwritten
        asm volatile("s_waitcnt lgkmcnt(0)" ::: "memory");
        __builtin_amdgcn_sched_barrier(0);

        if (ks < 4) STAGE_A(slot, ks + 2);  // overwrite this slot for step ks+2

        // fp32 -> f16 convert (16 v_cvt, RNE)
        half8 ah[2];
#pragma unroll
        for (int rt = 0; rt < 2; ++rt) {
            half8 t;
            t[0] = (_Float16)av[rt][0].x;
            t[1] = (_Float16)av[rt][0].y;
            t[2] = (_Float16)av[rt][0].z;
            t[3] = (_Float16)av[rt][0].w;
            t[4] = (_Float16)av[rt][1].x;
            t[5] = (_Float16)av[rt][1].y;
            t[6] = (_Float16)av[rt][1].z;
            t[7] = (_Float16)av[rt][1].w;
            ah[rt] = t;
        }

#pragma unroll
        for (int ct = 0; ct < 8; ++ct) {
#pragma unroll
            for (int rt = 0; rt < 2; ++rt)
                acc[rt][ct] = __builtin_amdgcn_mfma_f32_16x16x32_f16(ah[rt], bh[ct], acc[rt][ct], 0, 0, 0);
        }
    }
#undef STAGE_A
#undef WAITV

    // epilogue: one wave writes full 256B C-lines (col=ct*16+(l&15))
#pragma unroll
    for (int rt = 0; rt < 2; ++rt) {
        const int rb = rowbase + rt * 16 + (l >> 4) * 4;
#pragma unroll
        for (int j = 0; j < 4; ++j) {
            const int row = rb + j;
            if (row < M) {
#pragma unroll
                for (int ct = 0; ct < 8; ++ct)
                    C[(size_t)row * HH + ct * 16 + (l & 15)] = (_Float16)(acc[rt][ct][j] + bcol[ct]);
            }
        }
    }
}

// ---------------- Gather - product - neighbor-sum (fp16 tables) --------------
// out[b,h] = peProd[h] * sum_n RWh[r[b,n]][h] * prod_a VWh[e[a,b,n]][h]
__global__ __launch_bounds__(256) void gather_kernel(const int* __restrict__ r,
                                                     const int* __restrict__ e,
                                                     const _Float16* __restrict__ VWh,
                                                     const _Float16* __restrict__ RWh,
                                                     const float* __restrict__ peProd,
                                                     float* __restrict__ out) {
    __shared__ int rIdx[NN];
    __shared__ int eIdx[ARITY][NN];
    __shared__ float4 partial[3][16][2];

    const int b = blockIdx.x;
    const int tid = threadIdx.x;

    if (tid < NN) {
        rIdx[tid] = r[b * NN + tid];
    } else {
        int t = tid - NN;
        eIdx[t >> 6][t & 63] = e[(size_t)(t >> 6) * BB * NN + b * NN + (t & 63)];
    }
    __syncthreads();

    const int lane = tid & 63;
    const int wv = tid >> 6;    // 0..3
    const int q = lane >> 4;    // neighbor sub-slot 0..3
    const int ho = lane & 15;   // h-octet: h = ho*8 .. +8

    float acc8[8];
#pragma unroll
    for (int k = 0; k < 8; ++k) acc8[k] = 0.f;

#pragma unroll
    for (int it = 0; it < 4; ++it) {
        int n = it * 16 + wv * 4 + q;
        half8 rw = *(const half8*)(RWh + (size_t)rIdx[n] * HH + ho * 8);
        half8 v0 = *(const half8*)(VWh + (size_t)eIdx[0][n] * HH + ho * 8);
        half8 v1 = *(const half8*)(VWh + (size_t)eIdx[1][n] * HH + ho * 8);
        half8 v2 = *(const half8*)(VWh + (size_t)eIdx[2][n] * HH + ho * 8);
        half8 p = rw * v0;
        p = p * v1;
        p = p * v2;
#pragma unroll
        for (int k = 0; k < 8; ++k) acc8[k] += (float)p[k];
    }

    // combine the 4 neighbor sub-slots (lane quarters share ho)
#pragma unroll
    for (int k = 0; k < 8; ++k) {
        acc8[k] += __shfl_xor(acc8[k], 16);
        acc8[k] += __shfl_xor(acc8[k], 32);
    }

    if (wv > 0 && lane < 16) {
        partial[wv - 1][ho][0] = make_float4(acc8[0], acc8[1], acc8[2], acc8[3]);
        partial[wv - 1][ho][1] = make_float4(acc8[4], acc8[5], acc8[6], acc8[7]);
    }
    __syncthreads();
    if (wv == 0 && lane < 16) {
        float4 s0 = make_float4(acc8[0], acc8[1], acc8[2], acc8[3]);
        float4 s1 = make_float4(acc8[4], acc8[5], acc8[6], acc8[7]);
#pragma unroll
        for (int g = 0; g < 3; ++g) {
            float4 t0 = partial[g][ho][0], t1 = partial[g][ho][1];
            s0.x += t0.x; s0.y += t0.y; s0.z += t0.z; s0.w += t0.w;
            s1.x += t1.x; s1.y += t1.y; s1.z += t1.z; s1.w += t1.w;
        }
        float4 p0 = ((const float4*)peProd)[ho * 2];
        float4 p1 = ((const float4*)peProd)[ho * 2 + 1];
        ((float4*)(out + (size_t)b * HH))[ho * 2] =
            make_float4(s0.x * p0.x, s0.y * p0.y, s0.z * p0.z, s0.w * p0.w);
        ((float4*)(out + (size_t)b * HH))[ho * 2 + 1] =
            make_float4(s1.x * p1.x, s1.y * p1.y, s1.z * p1.z, s1.w * p1.w);
    }
}

// ---------------- Launch -----------------------------------------------------
extern "C" void kernel_launch(void* const* d_in, const int* in_sizes, int n_in,
                              void* d_out, int out_size, void* d_ws, size_t ws_size,
                              hipStream_t stream) {
    const int* r = (const int*)d_in[0];
    const int* e = (const int*)d_in[1];
    const float* V = (const float*)d_in[2];
    const float* R = (const float*)d_in[3];
    const float* P = (const float*)d_in[4];
    const float* WV = (const float*)d_in[5];
    const float* bV = (const float*)d_in[6];
    const float* WR = (const float*)d_in[7];
    const float* bR = (const float*)d_in[8];
    const float* WP = (const float*)d_in[9];
    const float* bP = (const float*)d_in[10];
    float* out = (float*)d_out;

    // ws layout: VWh [NUM_V,H] fp16 | RWh [NUM_R,H] fp16 | peProd [H] f32 | Wfrag 48 KB (f16)
    _Float16* VWh = (_Float16*)d_ws;
    _Float16* RWh = VWh + (size_t)NUM_V * HH;
    float* peProd = (float*)(RWh + (size_t)NUM_R * HH);
    unsigned short* wfrag = (unsigned short*)(peProd + HH);

    prep_kernel<<<81, 256, 0, stream>>>(R, WR, bR, RWh, WV, wfrag, P, WP, bP, peProd);
    gemm_bres<<<256, 832, 0, stream>>>(V, wfrag, bV, VWh, NUM_V);
    gather_kernel<<<BB, 256, 0, stream>>>(r, e, VWh, RWh, peProd, out);
}